// Round 7
// baseline (2024.299 us; speedup 1.0000x reference)
//
#include <hip/hip_runtime.h>
#include <cstdint>
#include <cstddef>

static constexpr int NPTS  = 4096;
static constexpr int NB    = 8;
static constexpr int NROWS = NB * NPTS;      // 32768
static constexpr int KNN   = 32;
static constexpr int CAP   = 384;            // survivor list capacity per row (4 quarters)
static constexpr int QCAP  = 96;             // per candidate-quarter capacity

typedef __attribute__((ext_vector_type(8))) short  bf16x8;
typedef __attribute__((ext_vector_type(4))) float  f32x4;

// ---------------- utility: 64-bit shuffles built from 32-bit ----------------
__device__ __forceinline__ unsigned long long shfl_xor_u64(unsigned long long v, int m) {
  int lo = __shfl_xor((int)(unsigned)(v & 0xFFFFFFFFULL), m, 64);
  int hi = __shfl_xor((int)(unsigned)(v >> 32), m, 64);
  return ((unsigned long long)(unsigned)hi << 32) | (unsigned)lo;
}
__device__ __forceinline__ unsigned long long shfl_u64(unsigned long long v, int src) {
  int lo = __shfl((int)(unsigned)(v & 0xFFFFFFFFULL), src, 64);
  int hi = __shfl((int)(unsigned)(v >> 32), src, 64);
  return ((unsigned long long)(unsigned)hi << 32) | (unsigned)lo;
}

// order-preserving float<->unsigned maps (for radix select over floats)
__device__ __forceinline__ unsigned f2o(float f) {
  unsigned u = __float_as_uint(f);
  return (u & 0x80000000u) ? ~u : (u | 0x80000000u);
}
__device__ __forceinline__ float o2f(unsigned o) {
  unsigned u = (o & 0x80000000u) ? (o ^ 0x80000000u) : ~o;
  return __uint_as_float(u);
}

// ---------------- squared norms per point ----------------
__global__ __launch_bounds__(256) void sqnorm_kernel(const float* __restrict__ x,
                                                     float* __restrict__ sq, int F) {
  int t = blockIdx.x * 256 + threadIdx.x;
  if (t >= NROWS) return;
  const float* p = x + (size_t)t * F;
  float s = 0.f;
  for (int f = 0; f < F; ++f) s = fmaf(p[f], p[f], s);
  sq[t] = s;
}

// ---------------- split fp32 -> bf16 hi + bf16 lo (RNE) ----------------
__global__ __launch_bounds__(256) void split_kernel(const float* __restrict__ x,
                                                    unsigned short* __restrict__ hi,
                                                    unsigned short* __restrict__ lo,
                                                    int total) {
  int t = blockIdx.x * 256 + threadIdx.x;
  if (t >= total) return;
  float v = x[t];
  unsigned u = __float_as_uint(v);
  unsigned h = (u + 0x7FFFu + ((u >> 16) & 1u)) >> 16;
  float hf = __uint_as_float(h << 16);
  float r = v - hf;
  unsigned ur = __float_as_uint(r);
  unsigned l = (ur + 0x7FFFu + ((ur >> 16) & 1u)) >> 16;
  hi[t] = (unsigned short)h;
  lo[t] = (unsigned short)l;
}

// ---------------- per-batch max of sq ----------------
__global__ __launch_bounds__(256) void batchmax_kernel(const float* __restrict__ sq,
                                                       float* __restrict__ sqmax) {
  int b = blockIdx.x, t = threadIdx.x;
  float m = 0.f;
  for (int i = t; i < NPTS; i += 256) m = fmaxf(m, sq[b * NPTS + i]);
  for (int off = 32; off >= 1; off >>= 1) m = fmaxf(m, __shfl_xor(m, off, 64));
  __shared__ float ls[4];
  if ((t & 63) == 0) ls[t >> 6] = m;
  __syncthreads();
  if (t == 0) sqmax[b] = fmaxf(fmaxf(ls[0], ls[1]), fmaxf(ls[2], ls[3]));
}

// =====================================================================
// Screen (F=64), R7: NO LDS, NO barriers. The candidate hi/lo slabs are
// 512 KB/batch and L2-resident with 256 blocks/batch reuse -- staging
// them in LDS was pure overhead (37.4 KB capped occupancy at 36%, plus
// 64 barriers and 16.7M bank-conflict cycles per dispatch). B-fragments
// are read directly from global: per sub, the wave's 64 lanes read
// 16 rows x 4 chunks = 1 KB contiguous -> fully coalesced L2 hits.
// Grid 2048 = 8 batches x 64 rowgroups x 4 cand-quarters; block owns
// 64 rows (4 waves x 16) and scans 1024 candidates (64 MFMA subs).
// Per-quarter T_q: exact 32nd-smallest of the quad's 64-value union
// (16 lanes x streaming top-4), radix-select over quad ballot slices
// (R6-validated). Soundness per quarter: >=32 quarter cands have
// d_approx <= T_q => overall exact 32nd <= T_q+eps => every exact lex
// top-32 member in quarter q has d_approx <= T_q+2eps -> admitted by
// its own quarter. Survivors to per-quarter glist segments (4 x 96),
// quad-ballot rank. gcnt[row*4+qtr] true counts (overflow -> fb).
// launch_bounds (256,6): allocator <=85 VGPR (no spill), occupancy
// floats up to VGPR-permitted (~8 blocks/CU at grid 2048).
// =====================================================================
__global__ __launch_bounds__(256, 6)
void knn_screen(const unsigned short* __restrict__ hi,
                const unsigned short* __restrict__ lo,
                const float* __restrict__ sq,
                const float* __restrict__ sqmax,
                int* __restrict__ gcnt,
                unsigned short* __restrict__ glist) {
  const int t = threadIdx.x, wave = t >> 6, lane = t & 63;
  const int l16 = lane & 15, quad = lane >> 4;
  const int bid = blockIdx.x;
  const int b    = bid & 7;                         // XCD-affine batch
  const int qtr  = (bid >> 3) & 3;                  // candidate quarter
  const int i0w  = ((bid >> 5) << 6) + (wave << 4); // this wave's 16 rows
  const int cbq  = qtr << 10;                       // candidate base
  const size_t base = (size_t)b * NPTS;
  const unsigned short* hib = hi + base * 64;
  const unsigned short* lob = lo + base * 64;
  const float* sqb = sq + base;
  const float sqm = sqmax[b];

  bf16x8 ahi[2], alo[2];
#pragma unroll
  for (int kb = 0; kb < 2; ++kb) {
    ahi[kb] = *(const bf16x8*)(hib + (size_t)(i0w + l16) * 64 + kb * 32 + quad * 8);
    alo[kb] = *(const bf16x8*)(lob + (size_t)(i0w + l16) * 64 + kb * 32 + quad * 8);
  }
  float sqi4[4];
#pragma unroll
  for (int reg = 0; reg < 4; ++reg) sqi4[reg] = sqb[i0w + quad * 4 + reg];

  float t1[4], t2[4], t3[4], t4[4], tinf4[4];
  int cnt4[4] = {0, 0, 0, 0};
#pragma unroll
  for (int reg = 0; reg < 4; ++reg) {
    t1[reg] = 3.4e38f; t2[reg] = 3.4e38f; t3[reg] = 3.4e38f; t4[reg] = 3.4e38f;
    tinf4[reg] = 0.f;
  }

  // ---------------- pass 0: streaming top-4 per (lane,reg) ----------------
  for (int sub = 0; sub < 64; ++sub) {
    const int jg = cbq + sub * 16 + l16;
    const unsigned short* hj = hib + (size_t)jg * 64 + quad * 8;
    const unsigned short* lj = lob + (size_t)jg * 64 + quad * 8;
    bf16x8 bh0 = *(const bf16x8*)(hj);
    bf16x8 bh1 = *(const bf16x8*)(hj + 32);
    bf16x8 bl0 = *(const bf16x8*)(lj);
    bf16x8 bl1 = *(const bf16x8*)(lj + 32);
    f32x4 acc = {0.f, 0.f, 0.f, 0.f};
    acc = __builtin_amdgcn_mfma_f32_16x16x32_bf16(ahi[0], bh0, acc, 0, 0, 0);
    acc = __builtin_amdgcn_mfma_f32_16x16x32_bf16(ahi[1], bh1, acc, 0, 0, 0);
    acc = __builtin_amdgcn_mfma_f32_16x16x32_bf16(ahi[0], bl0, acc, 0, 0, 0);
    acc = __builtin_amdgcn_mfma_f32_16x16x32_bf16(ahi[1], bl1, acc, 0, 0, 0);
    acc = __builtin_amdgcn_mfma_f32_16x16x32_bf16(alo[0], bh0, acc, 0, 0, 0);
    acc = __builtin_amdgcn_mfma_f32_16x16x32_bf16(alo[1], bh1, acc, 0, 0, 0);
    const float cs = sqb[jg];
#pragma unroll
    for (int reg = 0; reg < 4; ++reg) {   // C/D: col=l16, row=quad*4+reg
      float d = fmaf(-2.f, acc[reg], sqi4[reg] + cs);
      // sorted top-4 insert (sorting network)
      float m1 = fminf(d,  t1[reg]); float M1 = fmaxf(d,  t1[reg]);
      float m2 = fminf(M1, t2[reg]); float M2 = fmaxf(M1, t2[reg]);
      float m3 = fminf(M2, t3[reg]); float M3 = fmaxf(M2, t3[reg]);
      t1[reg] = m1; t2[reg] = m2; t3[reg] = m3;
      t4[reg] = fminf(M3, t4[reg]);
    }
  }

  // T_q = exact 32nd-smallest of the quad's 64 values (16 lanes x top-4)
#pragma unroll
  for (int reg = 0; reg < 4; ++reg) {
    unsigned c0s = f2o(t1[reg]);
    unsigned c1s = f2o(t2[reg]);
    unsigned c2s = f2o(t3[reg]);
    unsigned c3s = f2o(t4[reg]);
    unsigned prefix = 0;
    int need = 32;
    for (int bit = 31; bit >= 0; --bit) {
      unsigned hm = (bit == 31) ? 0u : ~((1u << (bit + 1)) - 1u);
      bool a0 = (((c0s ^ prefix) & hm) == 0u) && (((c0s >> bit) & 1u) == 0u);
      bool a1 = (((c1s ^ prefix) & hm) == 0u) && (((c1s >> bit) & 1u) == 0u);
      bool a2 = (((c2s ^ prefix) & hm) == 0u) && (((c2s >> bit) & 1u) == 0u);
      bool a3 = (((c3s ^ prefix) & hm) == 0u) && (((c3s >> bit) & 1u) == 0u);
      unsigned long long b0 = __ballot(a0);
      unsigned long long b1 = __ballot(a1);
      unsigned long long b2 = __ballot(a2);
      unsigned long long b3 = __ballot(a3);
      int cnt0 = __popc((unsigned)((b0 >> (quad * 16)) & 0xFFFFULL))
               + __popc((unsigned)((b1 >> (quad * 16)) & 0xFFFFULL))
               + __popc((unsigned)((b2 >> (quad * 16)) & 0xFFFFULL))
               + __popc((unsigned)((b3 >> (quad * 16)) & 0xFFFFULL));
      if (cnt0 < need) { need -= cnt0; prefix |= 1u << bit; }
    }
    float T = o2f(prefix);
    float eps = 6e-5f * (sqi4[reg] + sqm) + 1e-5f;
    tinf4[reg] = T + 2.f * eps;
  }

  // ---------------- pass 1: recompute, ballot-rank append ----------------
  for (int sub = 0; sub < 64; ++sub) {
    const int jg = cbq + sub * 16 + l16;
    const unsigned short* hj = hib + (size_t)jg * 64 + quad * 8;
    const unsigned short* lj = lob + (size_t)jg * 64 + quad * 8;
    bf16x8 bh0 = *(const bf16x8*)(hj);
    bf16x8 bh1 = *(const bf16x8*)(hj + 32);
    bf16x8 bl0 = *(const bf16x8*)(lj);
    bf16x8 bl1 = *(const bf16x8*)(lj + 32);
    f32x4 acc = {0.f, 0.f, 0.f, 0.f};
    acc = __builtin_amdgcn_mfma_f32_16x16x32_bf16(ahi[0], bh0, acc, 0, 0, 0);
    acc = __builtin_amdgcn_mfma_f32_16x16x32_bf16(ahi[1], bh1, acc, 0, 0, 0);
    acc = __builtin_amdgcn_mfma_f32_16x16x32_bf16(ahi[0], bl0, acc, 0, 0, 0);
    acc = __builtin_amdgcn_mfma_f32_16x16x32_bf16(ahi[1], bl1, acc, 0, 0, 0);
    acc = __builtin_amdgcn_mfma_f32_16x16x32_bf16(alo[0], bh0, acc, 0, 0, 0);
    acc = __builtin_amdgcn_mfma_f32_16x16x32_bf16(alo[1], bh1, acc, 0, 0, 0);
    const float cs = sqb[jg];
#pragma unroll
    for (int reg = 0; reg < 4; ++reg) {
      float d = fmaf(-2.f, acc[reg], sqi4[reg] + cs);
      bool keep = d <= tinf4[reg];
      unsigned long long mask = __ballot(keep);
      unsigned qm = (unsigned)((mask >> (quad * 16)) & 0xFFFFULL);
      if (qm) {
        int rank = __popc(qm & ((1u << l16) - 1u));
        if (keep) {
          int pos = cnt4[reg] + rank;
          if (pos < QCAP)
            glist[(size_t)(base + i0w + quad * 4 + reg) * CAP + qtr * QCAP + pos] =
                (unsigned short)jg;
        }
        cnt4[reg] += __popc(qm);
      }
    }
  }

  if (l16 == 0) {
#pragma unroll
    for (int reg = 0; reg < 4; ++reg)
      gcnt[(base + i0w + quad * 4 + reg) * 4 + qtr] = cnt4[reg];
  }
}

// =====================================================================
// Rerank MAIN path (spill-free; R5-validated structure). One wave per
// row; exact fp32 distances (bit-identical ascending c4 fma chain) on
// survivors from all 4 quarter-segments; exact lex-(dist,idx) top-32
// SET via 44-bit radix-select. Overflow rows -> knn_rerank_fb.
// =====================================================================
__global__ __launch_bounds__(256, 2)
void knn_rerank(const float* __restrict__ x, const float* __restrict__ sq,
                const int* __restrict__ gcnt,
                const unsigned short* __restrict__ glist,
                unsigned short* __restrict__ idx_out) {
  const int t = threadIdx.x, wave = t >> 6, lane = t & 63;
  const int row = blockIdx.x * 4 + wave;      // 0..32767
  const int b = row >> 12;
  const int i = row & (NPTS - 1);
  const float* xb  = x + (size_t)b * NPTS * 64;
  const float* sqb = sq + ((size_t)b << 12);

  const int n0 = gcnt[row * 4 + 0];
  const int n1 = gcnt[row * 4 + 1];
  const int n2 = gcnt[row * 4 + 2];
  const int n3 = gcnt[row * 4 + 3];
  if (n0 > QCAP || n1 > QCAP || n2 > QCAP || n3 > QCAP) return; // fb owns row

  const float sqi = sqb[i];
  float4 q[16];
#pragma unroll
  for (int c4 = 0; c4 < 16; ++c4)
    q[c4] = *(const float4*)(xb + (size_t)i * 64 + c4 * 4);

  const int n01  = n0 + n1;
  const int n012 = n01 + n2;
  const int n    = n012 + n3;                 // <= 384
  unsigned long long vk[6];
#pragma unroll
  for (int s = 0; s < 6; ++s) {
    int li = s * 64 + lane;
    unsigned long long v = 0xFFFFFFFFFFFULL;        // sentinel > any real
    if (li < n) {
      int sl = (li < n0)   ? li
             : (li < n01)  ? QCAP     + (li - n0)
             : (li < n012) ? 2 * QCAP + (li - n01)
                           : 3 * QCAP + (li - n012);
      int j = glist[(size_t)row * CAP + sl];
      const float4* xj = (const float4*)(xb + (size_t)j * 64);
      float dot = 0.f;
#pragma unroll
      for (int c4 = 0; c4 < 16; ++c4) {
        float4 c = xj[c4];
        dot = fmaf(q[c4].x, c.x, dot);
        dot = fmaf(q[c4].y, c.y, dot);
        dot = fmaf(q[c4].z, c.z, dot);
        dot = fmaf(q[c4].w, c.w, dot);
      }
      float d = fmaf(-2.f, dot, sqi + sqb[j]);
      unsigned u  = __float_as_uint(d);
      unsigned ck = (u & 0x80000000u) ? ~u : (u | 0x80000000u);
      v = ((unsigned long long)ck << 12) | (unsigned)j;
    }
    vk[s] = v;
  }
  // radix-select: prefix ends as the exact 32nd-smallest value (distinct)
  unsigned long long prefix = 0;
  int need = 32;
  for (int bit = 43; bit >= 0; --bit) {
    unsigned long long hm = (bit == 43) ? 0ULL
        : (~((1ULL << (bit + 1)) - 1ULL) & 0xFFFFFFFFFFFULL);
    int cnt0 = 0;
#pragma unroll
    for (int s = 0; s < 6; ++s) {
      bool a = ((vk[s] ^ prefix) & hm) == 0ULL;
      bool z = ((vk[s] >> bit) & 1ULL) == 0ULL;
      cnt0 += (int)__popcll(__ballot(a && z));
    }
    if (cnt0 < need) { need -= cnt0; prefix |= 1ULL << bit; }
  }
  int prev = 0;
#pragma unroll
  for (int s = 0; s < 6; ++s) {
    bool sel = vk[s] <= prefix;
    unsigned long long m = __ballot(sel);
    int rank = (int)__popcll(m & ((1ULL << lane) - 1ULL));
    if (sel)
      idx_out[(size_t)row * KNN + prev + rank] =
          (unsigned short)(vk[s] & 0xFFFULL);
    prev += (int)__popcll(m);
  }
}

// =====================================================================
// Rerank FALLBACK kernel (rare): early-exit on clean rows. Two-pass
// exact scan: per-lane min over own 64 cands -> 32-bit radix tau32 ->
// ballot-rank append survivors (cap 128) to LDS -> exact 44-bit lex
// radix-select. Tertiary: serial ballot-insert. Own kernel => own
// register budget: q[16] stays in VGPRs without constraining the main.
// =====================================================================
__global__ __launch_bounds__(256)
void knn_rerank_fb(const float* __restrict__ x, const float* __restrict__ sq,
                   const int* __restrict__ gcnt,
                   unsigned short* __restrict__ idx_out) {
  __shared__ unsigned long long fsurv[4][128];   // 4 KB, per-wave segments
  const int t = threadIdx.x, wave = t >> 6, lane = t & 63;
  const int row = blockIdx.x * 4 + wave;      // 0..32767
  const int b = row >> 12;
  const int i = row & (NPTS - 1);

  const int n0 = gcnt[row * 4 + 0];
  const int n1 = gcnt[row * 4 + 1];
  const int n2 = gcnt[row * 4 + 2];
  const int n3 = gcnt[row * 4 + 3];
  if (n0 <= QCAP && n1 <= QCAP && n2 <= QCAP && n3 <= QCAP) return;

  const float* xb  = x + (size_t)b * NPTS * 64;
  const float* sqb = sq + ((size_t)b << 12);
  const float sqi = sqb[i];

  float4 q[16];
#pragma unroll
  for (int c4 = 0; c4 < 16; ++c4)
    q[c4] = *(const float4*)(xb + (size_t)i * 64 + c4 * 4);

  // pass A: per-lane min of ck over own 64 candidates (j == lane mod 64)
  unsigned mnf = 0xFFFFFFFFu;
  for (int c0 = 0; c0 < NPTS; c0 += 64) {
    const int j = c0 + lane;
    const float4* xj = (const float4*)(xb + (size_t)j * 64);
    float dot = 0.f;
#pragma unroll
    for (int c4 = 0; c4 < 16; ++c4) {
      float4 c = xj[c4];
      dot = fmaf(q[c4].x, c.x, dot);
      dot = fmaf(q[c4].y, c.y, dot);
      dot = fmaf(q[c4].z, c.z, dot);
      dot = fmaf(q[c4].w, c.w, dot);
    }
    float d = fmaf(-2.f, dot, sqi + sqb[j]);
    unsigned u  = __float_as_uint(d);
    unsigned ck = (u & 0x80000000u) ? ~u : (u | 0x80000000u);
    mnf = ck < mnf ? ck : mnf;
  }
  // tau32 = exact 32nd-smallest of the 64 lane-mins
  unsigned tau32;
  {
    const unsigned v = mnf;
    unsigned prefix32 = 0;
    int need = 32;
    int act = 1;
    for (int bit = 31; bit >= 0; --bit) {
      const unsigned bv = (v >> bit) & 1u;
      unsigned long long m0 = __ballot(act && (bv == 0u));
      int c0n = (int)__popcll(m0);
      if (c0n >= need) {
        act = act && (bv == 0u);
      } else {
        need -= c0n;
        act = act && (bv == 1u);
        prefix32 |= (1u << bit);
      }
    }
    tau32 = prefix32;
  }
  // pass B: recompute, ballot-rank append survivors to LDS
  int cnt = 0;
  for (int c0 = 0; c0 < NPTS; c0 += 64) {
    const int j = c0 + lane;
    const float4* xj = (const float4*)(xb + (size_t)j * 64);
    float dot = 0.f;
#pragma unroll
    for (int c4 = 0; c4 < 16; ++c4) {
      float4 c = xj[c4];
      dot = fmaf(q[c4].x, c.x, dot);
      dot = fmaf(q[c4].y, c.y, dot);
      dot = fmaf(q[c4].z, c.z, dot);
      dot = fmaf(q[c4].w, c.w, dot);
    }
    float d = fmaf(-2.f, dot, sqi + sqb[j]);
    unsigned u  = __float_as_uint(d);
    unsigned ck = (u & 0x80000000u) ? ~u : (u | 0x80000000u);
    bool keep = ck <= tau32;
    unsigned long long mask = __ballot(keep);
    if (mask != 0ULL) {
      int rank = (int)__popcll(mask & ((1ULL << lane) - 1ULL));
      if (keep) {
        int pos = cnt + rank;
        if (pos < 128)
          fsurv[wave][pos] = ((unsigned long long)ck << 12) | (unsigned)j;
      }
      cnt += (int)__popcll(mask);
    }
  }
  if (cnt <= 128) {
    unsigned long long vk0 = (lane      < cnt) ? fsurv[wave][lane]      : 0xFFFFFFFFFFFULL;
    unsigned long long vk1 = (lane + 64 < cnt) ? fsurv[wave][lane + 64] : 0xFFFFFFFFFFFULL;
    unsigned long long prefix = 0;
    int need = 32;
    for (int bit = 43; bit >= 0; --bit) {
      unsigned long long hm = (bit == 43) ? 0ULL
          : (~((1ULL << (bit + 1)) - 1ULL) & 0xFFFFFFFFFFFULL);
      bool a0 = (((vk0 ^ prefix) & hm) == 0ULL) && (((vk0 >> bit) & 1ULL) == 0ULL);
      bool a1 = (((vk1 ^ prefix) & hm) == 0ULL) && (((vk1 >> bit) & 1ULL) == 0ULL);
      int cnt0 = (int)__popcll(__ballot(a0)) + (int)__popcll(__ballot(a1));
      if (cnt0 < need) { need -= cnt0; prefix |= 1ULL << bit; }
    }
    bool sel0 = vk0 <= prefix;
    unsigned long long m0 = __ballot(sel0);
    int rank0 = (int)__popcll(m0 & ((1ULL << lane) - 1ULL));
    if (sel0)
      idx_out[(size_t)row * KNN + rank0] = (unsigned short)(vk0 & 0xFFFULL);
    int prev = (int)__popcll(m0);
    bool sel1 = vk1 <= prefix;
    unsigned long long m1 = __ballot(sel1);
    int rank1 = (int)__popcll(m1 & ((1ULL << lane) - 1ULL));
    if (sel1)
      idx_out[(size_t)row * KNN + prev + rank1] = (unsigned short)(vk1 & 0xFFFULL);
  } else {
    // tertiary: exact full scan, validated serial ballot-insert
    unsigned long long ent = (0xFFFFFFFFFFFULL << 5) | (unsigned long long)(lane & 31);
    unsigned long long M   = (0xFFFFFFFFFFFULL << 5) | 31ULL;
    for (int c0 = 0; c0 < NPTS; c0 += 64) {
      const int j = c0 + lane;
      const float4* xj = (const float4*)(xb + (size_t)j * 64);
      float dot = 0.f;
#pragma unroll
      for (int c4 = 0; c4 < 16; ++c4) {
        float4 c = xj[c4];
        dot = fmaf(q[c4].x, c.x, dot);
        dot = fmaf(q[c4].y, c.y, dot);
        dot = fmaf(q[c4].z, c.z, dot);
        dot = fmaf(q[c4].w, c.w, dot);
      }
      float d = fmaf(-2.f, dot, sqi + sqb[j]);
      unsigned u  = __float_as_uint(d);
      unsigned ck = (u & 0x80000000u) ? ~u : (u | 0x80000000u);
      unsigned long long cq = ((unsigned long long)ck << 12) | (unsigned)j;
      unsigned long long mask = __ballot(cq < (M >> 5));
      while (mask) {
        const int src = __builtin_ctzll(mask);
        mask &= mask - 1;
        const unsigned long long bq = shfl_u64(cq, src);
        if (bq < (M >> 5)) {
          const unsigned slot = (unsigned)(M & 31ULL);
          if ((unsigned)(lane & 31) == slot) ent = (bq << 5) | slot;
          unsigned long long v = ent;
#pragma unroll
          for (int off = 16; off >= 1; off >>= 1) {
            unsigned long long w2 = shfl_xor_u64(v, off);
            v = (v > w2) ? v : w2;
          }
          M = v;
        }
      }
    }
    if (lane < 32)
      idx_out[(size_t)row * KNN + lane] =
          (unsigned short)((ent >> 5) & 0xFFFULL);
  }
}

// =====================================================================
// F=3 kNN: pass 1 (per-lane min + need=32 radix tau); pass 2 ballot-rank
// append of packed 44-bit keys to LDS (cap 128/row); exact lex radix-
// select. Overflow -> per-row exact full-scan fallback.
// =====================================================================
template <int F>
__global__ __launch_bounds__(256, 4) void knn_tiled(const float* __restrict__ x,
                                                    const float* __restrict__ sq,
                                                    unsigned short* __restrict__ idx_out) {
  constexpr int FP = 4;
  constexpr int TC = 256;
  constexpr int RPB = 32;
  constexpr int RPW = 8;
  constexpr int SCAP = 128;

  __shared__ __attribute__((aligned(16))) float qv[RPB][FP];
  __shared__ float qsq[RPB];
  __shared__ __attribute__((aligned(16))) float ct[TC][FP];
  __shared__ float csq[TC];
  __shared__ unsigned long long surv[RPB][SCAP];   // 32 KB

  const int t    = threadIdx.x;
  const int wave = t >> 6;
  const int lane = t & 63;
  const int rowbase = blockIdx.x << 5;
  const int b     = rowbase >> 12;
  const int ibase = rowbase & (NPTS - 1);
  const float* xb  = x + (size_t)b * NPTS * F;
  const float* sqb = sq + (b << 12);

  if (t < RPB) {
    qv[t][0] = xb[(size_t)(ibase + t) * 3 + 0];
    qv[t][1] = xb[(size_t)(ibase + t) * 3 + 1];
    qv[t][2] = xb[(size_t)(ibase + t) * 3 + 2];
    qv[t][3] = 0.f;
    qsq[t] = sqb[ibase + t];
  }
  __syncthreads();

  const int r0 = wave << 3;
  float4 q[RPW];
  float sqi[RPW];
#pragma unroll
  for (int rr = 0; rr < RPW; ++rr) {
    q[rr] = *reinterpret_cast<const float4*>(&qv[r0 + rr][0]);
    sqi[rr] = qsq[r0 + rr];
  }

  unsigned mn[RPW];
#pragma unroll
  for (int rr = 0; rr < RPW; ++rr) mn[rr] = 0xFFFFFFFFu;

  // ---------------- pass 1: per-lane min of ck ----------------
  for (int tile = 0; tile < NPTS / TC; ++tile) {
    __syncthreads();
    {
      int jg = tile * TC + t;
      ct[t][0] = xb[(size_t)jg * 3 + 0];
      ct[t][1] = xb[(size_t)jg * 3 + 1];
      ct[t][2] = xb[(size_t)jg * 3 + 2];
      ct[t][3] = 0.f;
      csq[t] = sqb[jg];
    }
    __syncthreads();

    float4 c0 = *reinterpret_cast<const float4*>(&ct[lane][0]);
    float4 c1 = *reinterpret_cast<const float4*>(&ct[lane + 64][0]);
    float4 c2 = *reinterpret_cast<const float4*>(&ct[lane + 128][0]);
    float4 c3 = *reinterpret_cast<const float4*>(&ct[lane + 192][0]);
    float cs[4];
#pragma unroll
    for (int s = 0; s < 4; ++s) cs[s] = csq[lane + 64 * s];

#pragma unroll
    for (int rr = 0; rr < RPW; ++rr) {
      float4 qq = q[rr];
      float dd[4];
      dd[0] = fmaf(qq.z, c0.z, fmaf(qq.y, c0.y, qq.x * c0.x));
      dd[1] = fmaf(qq.z, c1.z, fmaf(qq.y, c1.y, qq.x * c1.x));
      dd[2] = fmaf(qq.z, c2.z, fmaf(qq.y, c2.y, qq.x * c2.x));
      dd[3] = fmaf(qq.z, c3.z, fmaf(qq.y, c3.y, qq.x * c3.x));
#pragma unroll
      for (int s = 0; s < 4; ++s) {
        float d = fmaf(-2.f, dd[s], sqi[rr] + cs[s]);
        unsigned u  = __float_as_uint(d);
        unsigned ck = (u & 0x80000000u) ? ~u : (u | 0x80000000u);
        mn[rr] = ck < mn[rr] ? ck : mn[rr];
      }
    }
  }

  // tau[rr] = exact 32nd-smallest of the 64 lane-mins (radix over bits).
  unsigned tau[RPW];
#pragma unroll
  for (int rr = 0; rr < RPW; ++rr) {
    const unsigned v = mn[rr];
    unsigned prefix = 0;
    int need = 32;
    int act = 1;
    for (int bit = 31; bit >= 0; --bit) {
      const unsigned bv = (v >> bit) & 1u;
      unsigned long long m0 = __ballot(act && (bv == 0u));
      int c0n = (int)__popcll(m0);
      if (c0n >= need) {
        act = act && (bv == 0u);
      } else {
        need -= c0n;
        act = act && (bv == 1u);
        prefix |= (1u << bit);
      }
    }
    tau[rr] = prefix;
  }

  // ---------------- pass 2: ballot-rank append survivors ----------------
  int cnt[RPW];
#pragma unroll
  for (int rr = 0; rr < RPW; ++rr) cnt[rr] = 0;

  for (int tile = 0; tile < NPTS / TC; ++tile) {
    __syncthreads();
    {
      int jg = tile * TC + t;
      ct[t][0] = xb[(size_t)jg * 3 + 0];
      ct[t][1] = xb[(size_t)jg * 3 + 1];
      ct[t][2] = xb[(size_t)jg * 3 + 2];
      ct[t][3] = 0.f;
      csq[t] = sqb[jg];
    }
    __syncthreads();

    float4 c0 = *reinterpret_cast<const float4*>(&ct[lane][0]);
    float4 c1 = *reinterpret_cast<const float4*>(&ct[lane + 64][0]);
    float4 c2 = *reinterpret_cast<const float4*>(&ct[lane + 128][0]);
    float4 c3 = *reinterpret_cast<const float4*>(&ct[lane + 192][0]);
    float cs[4];
#pragma unroll
    for (int s = 0; s < 4; ++s) cs[s] = csq[lane + 64 * s];

#pragma unroll
    for (int rr = 0; rr < RPW; ++rr) {
      float4 qq = q[rr];
      float dd[4];
      dd[0] = fmaf(qq.z, c0.z, fmaf(qq.y, c0.y, qq.x * c0.x));
      dd[1] = fmaf(qq.z, c1.z, fmaf(qq.y, c1.y, qq.x * c1.x));
      dd[2] = fmaf(qq.z, c2.z, fmaf(qq.y, c2.y, qq.x * c2.x));
      dd[3] = fmaf(qq.z, c3.z, fmaf(qq.y, c3.y, qq.x * c3.x));
#pragma unroll
      for (int s = 0; s < 4; ++s) {
        float d = fmaf(-2.f, dd[s], sqi[rr] + cs[s]);
        unsigned u  = __float_as_uint(d);
        unsigned ck = (u & 0x80000000u) ? ~u : (u | 0x80000000u);
        bool keep = ck <= tau[rr];
        unsigned long long mask = __ballot(keep);
        if (mask != 0ULL) {
          int rank = (int)__popcll(mask & ((1ULL << lane) - 1ULL));
          if (keep) {
            int pos = cnt[rr] + rank;
            if (pos < SCAP)
              surv[r0 + rr][pos] =
                  ((unsigned long long)ck << 12) |
                  (unsigned)(tile * TC + s * 64 + lane);
          }
          cnt[rr] += (int)__popcll(mask);
        }
      }
    }
  }

  // ---------------- exact lex top-32 per row via radix-select ----------------
#pragma unroll
  for (int rr = 0; rr < RPW; ++rr) {
    const int row = rowbase + r0 + rr;
    const int n = cnt[rr];
    if (n <= SCAP) {
      unsigned long long vk0 = (lane      < n) ? surv[r0 + rr][lane]      : 0xFFFFFFFFFFFULL;
      unsigned long long vk1 = (lane + 64 < n) ? surv[r0 + rr][lane + 64] : 0xFFFFFFFFFFFULL;
      unsigned long long prefix = 0;
      int need = 32;
      for (int bit = 43; bit >= 0; --bit) {
        unsigned long long hm = (bit == 43) ? 0ULL
            : (~((1ULL << (bit + 1)) - 1ULL) & 0xFFFFFFFFFFFULL);
        bool a0 = (((vk0 ^ prefix) & hm) == 0ULL) && (((vk0 >> bit) & 1ULL) == 0ULL);
        bool a1 = (((vk1 ^ prefix) & hm) == 0ULL) && (((vk1 >> bit) & 1ULL) == 0ULL);
        int cnt0 = (int)__popcll(__ballot(a0)) + (int)__popcll(__ballot(a1));
        if (cnt0 < need) { need -= cnt0; prefix |= 1ULL << bit; }
      }
      bool sel0 = vk0 <= prefix;
      unsigned long long m0 = __ballot(sel0);
      int rank0 = (int)__popcll(m0 & ((1ULL << lane) - 1ULL));
      if (sel0)
        idx_out[(row << 5) + rank0] = (unsigned short)(vk0 & 0xFFFULL);
      int prev = (int)__popcll(m0);
      bool sel1 = vk1 <= prefix;
      unsigned long long m1 = __ballot(sel1);
      int rank1 = (int)__popcll(m1 & ((1ULL << lane) - 1ULL));
      if (sel1)
        idx_out[(row << 5) + prev + rank1] = (unsigned short)(vk1 & 0xFFFULL);
    } else {
      // overflow fallback: exact full scan with validated ballot-insert
      unsigned long long ent = (0xFFFFFFFFFFFULL << 5) | (unsigned long long)(lane & 31);
      unsigned long long M   = (0xFFFFFFFFFFFULL << 5) | 31ULL;
      const float4 qq = q[rr];
      const float si = sqi[rr];
      for (int c0i = 0; c0i < NPTS; c0i += 64) {
        const int j = c0i + lane;
        const float dd_ = fmaf(qq.z, xb[(size_t)j * 3 + 2],
                           fmaf(qq.y, xb[(size_t)j * 3 + 1],
                                qq.x * xb[(size_t)j * 3 + 0]));
        float d = fmaf(-2.f, dd_, si + sqb[j]);
        unsigned u  = __float_as_uint(d);
        unsigned ck = (u & 0x80000000u) ? ~u : (u | 0x80000000u);
        unsigned long long cq = ((unsigned long long)ck << 12) | (unsigned)j;
        unsigned long long mask = __ballot(cq < (M >> 5));
        while (mask) {
          const int src = __builtin_ctzll(mask);
          mask &= mask - 1;
          const unsigned long long bq = shfl_u64(cq, src);
          if (bq < (M >> 5)) {
            const unsigned slot = (unsigned)(M & 31ULL);
            if ((unsigned)(lane & 31) == slot) ent = (bq << 5) | slot;
            unsigned long long v = ent;
#pragma unroll
            for (int off = 16; off >= 1; off >>= 1) {
              unsigned long long w2 = shfl_xor_u64(v, off);
              v = (v > w2) ? v : w2;
            }
            M = v;
          }
        }
      }
      if (lane < 32)
        idx_out[(row << 5) + lane] = (unsigned short)((ent >> 5) & 0xFFFULL);
    }
  }
}

// ---------------- per-node P = x.Wbot ; C = x.(Wtop-Wbot) + b ----------------
__global__ __launch_bounds__(256) void mlp_pc_kernel(const float* __restrict__ xin,
                                                     const float* __restrict__ W,
                                                     const float* __restrict__ bias,
                                                     float* __restrict__ P,
                                                     float* C,
                                                     int F, int O, int total) {
  int t = blockIdx.x * 256 + threadIdx.x;
  if (t >= total) return;
  int n = t / O, o = t % O;
  const float* xr = xin + (size_t)n * F;
  const float* Wt = W + o;
  const float* Wb = W + (size_t)F * O + o;
  float p = 0.f, c = 0.f;
  for (int f = 0; f < F; ++f) {
    float a  = xr[f];
    float wt = Wt[(size_t)f * O];
    float wb = Wb[(size_t)f * O];
    p = fmaf(a, wb, p);
    c = fmaf(a, wt - wb, c);
  }
  P[t] = p;
  C[t] = c + bias[o];
}

// ---------------- h[t] (pre-filled with C) += max_k P[idx_k] ----------------
__global__ __launch_bounds__(256) void aggregate_kernel(const unsigned short* __restrict__ idx,
                                                        const float* __restrict__ P,
                                                        float* h, int O, int total) {
  int t = blockIdx.x * 256 + threadIdx.x;
  if (t >= total) return;
  int n = t / O, o = t % O;
  const unsigned short* ix = idx + (size_t)n * KNN;
  const int rowbase = (n >> 12) << 12;
  float m = -3.402823466e+38f;
  for (int k = 0; k < KNN; ++k) {
    int jg = rowbase + ix[k];
    float v = P[(size_t)jg * O + o];
    m = fmaxf(m, v);
  }
  h[t] = h[t] + m;
}

// ---------------- BN stats over relu(h): mean + invstd per channel ----------
__global__ __launch_bounds__(256) void bn_stats_kernel(const float* __restrict__ h,
                                                       float* __restrict__ stats) {
  const int c = blockIdx.x;
  const int t = threadIdx.x;
  double s = 0.0, s2 = 0.0;
  for (int n = t; n < NROWS; n += 256) {
    float v = h[(size_t)n * 64 + c];
    v = v > 0.f ? v : 0.f;
    s += v;
    s2 += (double)v * v;
  }
  __shared__ double ls[256], ls2[256];
  ls[t] = s; ls2[t] = s2;
  __syncthreads();
  for (int st = 128; st; st >>= 1) {
    if (t < st) { ls[t] += ls[t + st]; ls2[t] += ls2[t + st]; }
    __syncthreads();
  }
  if (t == 0) {
    double mean = ls[0] / (double)NROWS;
    double var  = ls2[0] / (double)NROWS - mean * mean;
    stats[c]      = (float)mean;
    stats[64 + c] = (float)(1.0 / sqrt(var + 1e-5));
  }
}

// ---------------- apply: out = (relu(h)-mean)*invstd*g + be ----------------
__global__ __launch_bounds__(256) void bn_apply_kernel(const float* h,
                                                       const float* __restrict__ stats,
                                                       const float* __restrict__ g,
                                                       const float* __restrict__ be,
                                                       float* out, int total) {
  int t = blockIdx.x * 256 + threadIdx.x;
  if (t >= total) return;
  int ch = t & 63;
  float v = fmaxf(h[t], 0.f);
  out[t] = (v - stats[ch]) * stats[64 + ch] * g[ch] + be[ch];
}

// ---------------- write h3 to out + per-block loss partials ----------------
__global__ __launch_bounds__(256) void final_kernel(const float* __restrict__ h3,
                                                    const float* __restrict__ target,
                                                    float* __restrict__ out,
                                                    double* __restrict__ partial) {
  double s = 0.0;
  for (int t = blockIdx.x * 256 + threadIdx.x; t < NROWS * 3; t += 256 * 256) {
    float v = h3[t];
    out[t] = v;
    float d = v - target[t];
    s += (double)d * d;
  }
  __shared__ double ls[256];
  int t = threadIdx.x;
  ls[t] = s;
  __syncthreads();
  for (int st = 128; st; st >>= 1) {
    if (t < st) ls[t] += ls[t + st];
    __syncthreads();
  }
  if (t == 0) partial[blockIdx.x] = ls[0];
}

__global__ __launch_bounds__(256) void loss_kernel(const double* __restrict__ partial,
                                                   float* __restrict__ out) {
  int t = threadIdx.x;
  __shared__ double ls[256];
  ls[t] = partial[t];
  __syncthreads();
  for (int st = 128; st; st >>= 1) {
    if (t < st) ls[t] += ls[t + st];
    __syncthreads();
  }
  if (t == 0) out[NROWS * 3] = (float)(ls[0] / (double)(NROWS * 3));
}

// ---------------- driver ----------------
extern "C" void kernel_launch(void* const* d_in, const int* in_sizes, int n_in,
                              void* d_out, int out_size, void* d_ws, size_t ws_size,
                              hipStream_t stream) {
  const float* x   = (const float*)d_in[0];
  const float* tgt = (const float*)d_in[1];
  const float* W1  = (const float*)d_in[2];
  const float* b1  = (const float*)d_in[3];
  const float* g1  = (const float*)d_in[4];
  const float* be1 = (const float*)d_in[5];
  const float* W2  = (const float*)d_in[6];
  const float* b2  = (const float*)d_in[7];
  const float* g2  = (const float*)d_in[8];
  const float* be2 = (const float*)d_in[9];
  const float* W3  = (const float*)d_in[10];
  const float* b3  = (const float*)d_in[11];
  float* out = (float*)d_out;

  char* ws = (char*)d_ws;
  size_t off = 0;
  float* sq    = (float*)(ws + off); off += (size_t)NROWS * 4;           // 128 KB
  unsigned short* idxb = (unsigned short*)(ws + off); off += (size_t)NROWS * KNN * 2; // 2 MB
  float* P     = (float*)(ws + off); off += (size_t)NROWS * 64 * 4;      // 8 MB
  float* CA    = (float*)(ws + off); off += (size_t)NROWS * 64 * 4;      // 8 MB
  float* CB    = (float*)(ws + off); off += (size_t)NROWS * 64 * 4;      // 8 MB
  int*   gcnt  = (int*)(ws + off);   off += (size_t)NROWS * 16;          // 512 KB (4 quarters)
  unsigned short* glist = (unsigned short*)(ws + off); off += (size_t)NROWS * CAP * 2; // 25.2 MB
  float* stats = (float*)(ws + off); off += 256 * 4;
  float* sqmax = (float*)(ws + off); off += 64;
  double* part = (double*)(ws + off); off += 256 * 8;

  // hi/lo (bf16, 4 MB each) alias P (8 MB): P is dead during screen/rerank.
  unsigned short* hib = (unsigned short*)P;
  unsigned short* lob = hib + (size_t)NROWS * 64;

  const int T64 = NROWS * 64;
  const int T3  = NROWS * 3;

  // ---- layer 1 (F=3 -> 64), VALU kNN ----
  sqnorm_kernel<<<NROWS / 256, 256, 0, stream>>>(x, sq, 3);
  knn_tiled<3><<<NROWS / 32, 256, 0, stream>>>(x, sq, idxb);
  mlp_pc_kernel<<<T64 / 256, 256, 0, stream>>>(x, W1, b1, P, CA, 3, 64, T64);
  aggregate_kernel<<<T64 / 256, 256, 0, stream>>>(idxb, P, CA, 64, T64);
  bn_stats_kernel<<<64, 256, 0, stream>>>(CA, stats);
  bn_apply_kernel<<<T64 / 256, 256, 0, stream>>>(CA, stats, g1, be1, CA, T64);

  // ---- layer 2 (F=64 -> 64), MFMA screen + exact rerank ----
  sqnorm_kernel<<<NROWS / 256, 256, 0, stream>>>(CA, sq, 64);
  split_kernel<<<T64 / 256, 256, 0, stream>>>(CA, hib, lob, T64);
  batchmax_kernel<<<NB, 256, 0, stream>>>(sq, sqmax);
  knn_screen<<<2048, 256, 0, stream>>>(hib, lob, sq, sqmax, gcnt, glist);
  knn_rerank<<<NROWS / 4, 256, 0, stream>>>(CA, sq, gcnt, glist, idxb);
  knn_rerank_fb<<<NROWS / 4, 256, 0, stream>>>(CA, sq, gcnt, idxb);
  mlp_pc_kernel<<<T64 / 256, 256, 0, stream>>>(CA, W2, b2, P, CB, 64, 64, T64);
  aggregate_kernel<<<T64 / 256, 256, 0, stream>>>(idxb, P, CB, 64, T64);
  bn_stats_kernel<<<64, 256, 0, stream>>>(CB, stats);
  bn_apply_kernel<<<T64 / 256, 256, 0, stream>>>(CB, stats, g2, be2, CB, T64);

  // ---- layer 3 (F=64 -> 3), MFMA screen + exact rerank ----
  sqnorm_kernel<<<NROWS / 256, 256, 0, stream>>>(CB, sq, 64);
  split_kernel<<<T64 / 256, 256, 0, stream>>>(CB, hib, lob, T64);
  batchmax_kernel<<<NB, 256, 0, stream>>>(sq, sqmax);
  knn_screen<<<2048, 256, 0, stream>>>(hib, lob, sq, sqmax, gcnt, glist);
  knn_rerank<<<NROWS / 4, 256, 0, stream>>>(CB, sq, gcnt, glist, idxb);
  knn_rerank_fb<<<NROWS / 4, 256, 0, stream>>>(CB, sq, gcnt, idxb);
  mlp_pc_kernel<<<T3 / 256, 256, 0, stream>>>(CB, W3, b3, P, CA, 64, 3, T3);
  aggregate_kernel<<<T3 / 256, 256, 0, stream>>>(idxb, P, CA, 3, T3);

  // ---- output + loss ----
  final_kernel<<<256, 256, 0, stream>>>(CA, tgt, out, part);
  loss_kernel<<<1, 256, 0, stream>>>(part, out);
}

// Round 8
// 1477.605 us; speedup vs baseline: 1.3700x; 1.3700x over previous
//
#include <hip/hip_runtime.h>
#include <cstdint>
#include <cstddef>

static constexpr int NPTS  = 4096;
static constexpr int NB    = 8;
static constexpr int NROWS = NB * NPTS;      // 32768
static constexpr int KNN   = 32;
static constexpr int CAP   = 384;            // survivor list capacity per row (4 quarters)
static constexpr int QCAP  = 96;             // per candidate-quarter capacity

typedef __attribute__((ext_vector_type(8))) short  bf16x8;
typedef __attribute__((ext_vector_type(4))) float  f32x4;

// ---------------- utility: 64-bit shuffles built from 32-bit ----------------
__device__ __forceinline__ unsigned long long shfl_xor_u64(unsigned long long v, int m) {
  int lo = __shfl_xor((int)(unsigned)(v & 0xFFFFFFFFULL), m, 64);
  int hi = __shfl_xor((int)(unsigned)(v >> 32), m, 64);
  return ((unsigned long long)(unsigned)hi << 32) | (unsigned)lo;
}
__device__ __forceinline__ unsigned long long shfl_u64(unsigned long long v, int src) {
  int lo = __shfl((int)(unsigned)(v & 0xFFFFFFFFULL), src, 64);
  int hi = __shfl((int)(unsigned)(v >> 32), src, 64);
  return ((unsigned long long)(unsigned)hi << 32) | (unsigned)lo;
}

// order-preserving float<->unsigned maps (for radix select over floats)
__device__ __forceinline__ unsigned f2o(float f) {
  unsigned u = __float_as_uint(f);
  return (u & 0x80000000u) ? ~u : (u | 0x80000000u);
}
__device__ __forceinline__ float o2f(unsigned o) {
  unsigned u = (o & 0x80000000u) ? (o ^ 0x80000000u) : ~o;
  return __uint_as_float(u);
}

// ---------------- squared norms per point ----------------
__global__ __launch_bounds__(256) void sqnorm_kernel(const float* __restrict__ x,
                                                     float* __restrict__ sq, int F) {
  int t = blockIdx.x * 256 + threadIdx.x;
  if (t >= NROWS) return;
  const float* p = x + (size_t)t * F;
  float s = 0.f;
  for (int f = 0; f < F; ++f) s = fmaf(p[f], p[f], s);
  sq[t] = s;
}

// =====================================================================
// split fp32 -> bf16 hi + lo (RNE), written in MFMA-FRAGMENT-MAJOR
// layout (R8): for batch b, 16-cand tile g, piece p (feats p*32..),
// chunk index (quad*16 + l16) holds cand (g*16+l16), feats
// p*32+quad*8..+8. Screen then loads every A/B fragment as
// base + lane*16B: one fully-coalesced 1KB transaction (R7's direct
// row-major loads were 128B-stride gathers -> 16 cache lines/instr,
// which is why no-LDS regressed 250->515us).
// =====================================================================
__global__ __launch_bounds__(256) void split_kernel(const float* __restrict__ x,
                                                    unsigned short* __restrict__ hi,
                                                    unsigned short* __restrict__ lo,
                                                    int total) {
  int t = blockIdx.x * 256 + threadIdx.x;
  if (t >= total) return;
  float v = x[t];
  unsigned u = __float_as_uint(v);
  unsigned h = (u + 0x7FFFu + ((u >> 16) & 1u)) >> 16;
  float hf = __uint_as_float(h << 16);
  float r = v - hf;
  unsigned ur = __float_as_uint(r);
  unsigned l = (ur + 0x7FFFu + ((ur >> 16) & 1u)) >> 16;

  const int n = t >> 6;            // row
  const int f = t & 63;            // feature
  const int b   = n >> 12;
  const int g   = (n >> 4) & 255;  // 16-row tile within batch
  const int l16 = n & 15;
  const int p    = f >> 5;         // piece (feats 0-31 / 32-63)
  const int quad = (f >> 3) & 3;
  const int w    = f & 7;
  const size_t dst = ((((size_t)b * 256 + g) * 2 + p) << 9)   // tile-piece base (512 shorts)
                   + (size_t)(quad * 16 + l16) * 8 + w;
  hi[dst] = (unsigned short)h;
  lo[dst] = (unsigned short)l;
}

// ---------------- per-batch max of sq ----------------
__global__ __launch_bounds__(256) void batchmax_kernel(const float* __restrict__ sq,
                                                       float* __restrict__ sqmax) {
  int b = blockIdx.x, t = threadIdx.x;
  float m = 0.f;
  for (int i = t; i < NPTS; i += 256) m = fmaxf(m, sq[b * NPTS + i]);
  for (int off = 32; off >= 1; off >>= 1) m = fmaxf(m, __shfl_xor(m, off, 64));
  __shared__ float ls[4];
  if ((t & 63) == 0) ls[t >> 6] = m;
  __syncthreads();
  if (t == 0) sqmax[b] = fmaxf(fmaxf(ls[0], ls[1]), fmaxf(ls[2], ls[3]));
}

// =====================================================================
// Screen (F=64), R8: no LDS, no barriers, FRAGMENT-MAJOR global loads
// (every A/B fragment = coalesced 1KB, L2-resident 256KB/quarter slab
// shared by 64 rowgroup-blocks). Grid 2048 = 8 batches x 64 rowgroups
// x 4 cand-quarters; block owns 64 rows (4 waves x 16), scans 1024
// cands (64 MFMA subs). Per-quarter T_q = exact 32nd-smallest of the
// quad's 64-value union (16 lanes x streaming top-4), radix-select
// over quad ballot slices (R6-validated). Soundness: >=32 quarter
// cands <= T_q => overall exact 32nd <= T_q+eps => every exact lex
// top-32 member in quarter q has d_approx <= T_q+2eps. Survivors to
// per-quarter glist segments (4 x 96), quad-ballot rank.
// launch_bounds (256,4): <=128 VGPR so the compiler can pipeline
// loads across subs (R7's (256,6) -> VGPR=40 serialized L2 latency).
// =====================================================================
__global__ __launch_bounds__(256, 4)
void knn_screen(const unsigned short* __restrict__ hi,
                const unsigned short* __restrict__ lo,
                const float* __restrict__ sq,
                const float* __restrict__ sqmax,
                int* __restrict__ gcnt,
                unsigned short* __restrict__ glist) {
  const int t = threadIdx.x, wave = t >> 6, lane = t & 63;
  const int l16 = lane & 15, quad = lane >> 4;
  const int bid = blockIdx.x;
  const int b    = bid & 7;                         // XCD-affine batch
  const int qtr  = (bid >> 3) & 3;                  // candidate quarter
  const int i0w  = ((bid >> 5) << 6) + (wave << 4); // this wave's 16 rows
  const int cbq  = qtr << 10;                       // candidate base (rows)
  const size_t base = (size_t)b * NPTS;
  const unsigned short* hib = hi + base * 64;       // batch frag base
  const unsigned short* lob = lo + base * 64;
  const float* sqb = sq + base;
  const float sqm = sqmax[b];
  const int laneoff = lane * 8;

  // A fragments: tile g_A = i0w>>4, piece kb -> coalesced 1KB loads
  bf16x8 ahi[2], alo[2];
#pragma unroll
  for (int kb = 0; kb < 2; ++kb) {
    const size_t abase = ((size_t)((i0w >> 4) * 2 + kb) << 9);
    ahi[kb] = *(const bf16x8*)(hib + abase + laneoff);
    alo[kb] = *(const bf16x8*)(lob + abase + laneoff);
  }
  float sqi4[4];
#pragma unroll
  for (int reg = 0; reg < 4; ++reg) sqi4[reg] = sqb[i0w + quad * 4 + reg];

  float t1[4], t2[4], t3[4], t4[4], tinf4[4];
  int cnt4[4] = {0, 0, 0, 0};
#pragma unroll
  for (int reg = 0; reg < 4; ++reg) {
    t1[reg] = 3.4e38f; t2[reg] = 3.4e38f; t3[reg] = 3.4e38f; t4[reg] = 3.4e38f;
    tinf4[reg] = 0.f;
  }

  // ---------------- pass 0: streaming top-4 per (lane,reg) ----------------
#pragma unroll 2
  for (int sub = 0; sub < 64; ++sub) {
    const size_t bb = ((size_t)((qtr * 64 + sub) * 2) << 9);
    bf16x8 bh0 = *(const bf16x8*)(hib + bb + laneoff);
    bf16x8 bh1 = *(const bf16x8*)(hib + bb + 512 + laneoff);
    bf16x8 bl0 = *(const bf16x8*)(lob + bb + laneoff);
    bf16x8 bl1 = *(const bf16x8*)(lob + bb + 512 + laneoff);
    f32x4 acc = {0.f, 0.f, 0.f, 0.f};
    acc = __builtin_amdgcn_mfma_f32_16x16x32_bf16(ahi[0], bh0, acc, 0, 0, 0);
    acc = __builtin_amdgcn_mfma_f32_16x16x32_bf16(ahi[1], bh1, acc, 0, 0, 0);
    acc = __builtin_amdgcn_mfma_f32_16x16x32_bf16(ahi[0], bl0, acc, 0, 0, 0);
    acc = __builtin_amdgcn_mfma_f32_16x16x32_bf16(ahi[1], bl1, acc, 0, 0, 0);
    acc = __builtin_amdgcn_mfma_f32_16x16x32_bf16(alo[0], bh0, acc, 0, 0, 0);
    acc = __builtin_amdgcn_mfma_f32_16x16x32_bf16(alo[1], bh1, acc, 0, 0, 0);
    const float cs = sqb[cbq + sub * 16 + l16];
#pragma unroll
    for (int reg = 0; reg < 4; ++reg) {   // C/D: col=l16, row=quad*4+reg
      float d = fmaf(-2.f, acc[reg], sqi4[reg] + cs);
      // sorted top-4 insert (sorting network)
      float m1 = fminf(d,  t1[reg]); float M1 = fmaxf(d,  t1[reg]);
      float m2 = fminf(M1, t2[reg]); float M2 = fmaxf(M1, t2[reg]);
      float m3 = fminf(M2, t3[reg]); float M3 = fmaxf(M2, t3[reg]);
      t1[reg] = m1; t2[reg] = m2; t3[reg] = m3;
      t4[reg] = fminf(M3, t4[reg]);
    }
  }

  // T_q = exact 32nd-smallest of the quad's 64 values (16 lanes x top-4)
#pragma unroll
  for (int reg = 0; reg < 4; ++reg) {
    unsigned c0s = f2o(t1[reg]);
    unsigned c1s = f2o(t2[reg]);
    unsigned c2s = f2o(t3[reg]);
    unsigned c3s = f2o(t4[reg]);
    unsigned prefix = 0;
    int need = 32;
    for (int bit = 31; bit >= 0; --bit) {
      unsigned hm = (bit == 31) ? 0u : ~((1u << (bit + 1)) - 1u);
      bool a0 = (((c0s ^ prefix) & hm) == 0u) && (((c0s >> bit) & 1u) == 0u);
      bool a1 = (((c1s ^ prefix) & hm) == 0u) && (((c1s >> bit) & 1u) == 0u);
      bool a2 = (((c2s ^ prefix) & hm) == 0u) && (((c2s >> bit) & 1u) == 0u);
      bool a3 = (((c3s ^ prefix) & hm) == 0u) && (((c3s >> bit) & 1u) == 0u);
      unsigned long long b0 = __ballot(a0);
      unsigned long long b1 = __ballot(a1);
      unsigned long long b2 = __ballot(a2);
      unsigned long long b3 = __ballot(a3);
      int cnt0 = __popc((unsigned)((b0 >> (quad * 16)) & 0xFFFFULL))
               + __popc((unsigned)((b1 >> (quad * 16)) & 0xFFFFULL))
               + __popc((unsigned)((b2 >> (quad * 16)) & 0xFFFFULL))
               + __popc((unsigned)((b3 >> (quad * 16)) & 0xFFFFULL));
      if (cnt0 < need) { need -= cnt0; prefix |= 1u << bit; }
    }
    float T = o2f(prefix);
    float eps = 6e-5f * (sqi4[reg] + sqm) + 1e-5f;
    tinf4[reg] = T + 2.f * eps;
  }

  // ---------------- pass 1: recompute, ballot-rank append ----------------
#pragma unroll 2
  for (int sub = 0; sub < 64; ++sub) {
    const size_t bb = ((size_t)((qtr * 64 + sub) * 2) << 9);
    bf16x8 bh0 = *(const bf16x8*)(hib + bb + laneoff);
    bf16x8 bh1 = *(const bf16x8*)(hib + bb + 512 + laneoff);
    bf16x8 bl0 = *(const bf16x8*)(lob + bb + laneoff);
    bf16x8 bl1 = *(const bf16x8*)(lob + bb + 512 + laneoff);
    f32x4 acc = {0.f, 0.f, 0.f, 0.f};
    acc = __builtin_amdgcn_mfma_f32_16x16x32_bf16(ahi[0], bh0, acc, 0, 0, 0);
    acc = __builtin_amdgcn_mfma_f32_16x16x32_bf16(ahi[1], bh1, acc, 0, 0, 0);
    acc = __builtin_amdgcn_mfma_f32_16x16x32_bf16(ahi[0], bl0, acc, 0, 0, 0);
    acc = __builtin_amdgcn_mfma_f32_16x16x32_bf16(ahi[1], bl1, acc, 0, 0, 0);
    acc = __builtin_amdgcn_mfma_f32_16x16x32_bf16(alo[0], bh0, acc, 0, 0, 0);
    acc = __builtin_amdgcn_mfma_f32_16x16x32_bf16(alo[1], bh1, acc, 0, 0, 0);
    const int jg0 = cbq + sub * 16 + l16;
    const float cs = sqb[jg0];
#pragma unroll
    for (int reg = 0; reg < 4; ++reg) {
      float d = fmaf(-2.f, acc[reg], sqi4[reg] + cs);
      bool keep = d <= tinf4[reg];
      unsigned long long mask = __ballot(keep);
      unsigned qm = (unsigned)((mask >> (quad * 16)) & 0xFFFFULL);
      if (qm) {
        int rank = __popc(qm & ((1u << l16) - 1u));
        if (keep) {
          int pos = cnt4[reg] + rank;
          if (pos < QCAP)
            glist[(size_t)(base + i0w + quad * 4 + reg) * CAP + qtr * QCAP + pos] =
                (unsigned short)jg0;
        }
        cnt4[reg] += __popc(qm);
      }
    }
  }

  if (l16 == 0) {
#pragma unroll
    for (int reg = 0; reg < 4; ++reg)
      gcnt[(base + i0w + quad * 4 + reg) * 4 + qtr] = cnt4[reg];
  }
}

// =====================================================================
// Rerank MAIN path (spill-free; R5-validated structure). One wave per
// row; exact fp32 distances (bit-identical ascending c4 fma chain) on
// survivors from all 4 quarter-segments; exact lex-(dist,idx) top-32
// SET via 44-bit radix-select. Overflow rows -> knn_rerank_fb.
// =====================================================================
__global__ __launch_bounds__(256, 2)
void knn_rerank(const float* __restrict__ x, const float* __restrict__ sq,
                const int* __restrict__ gcnt,
                const unsigned short* __restrict__ glist,
                unsigned short* __restrict__ idx_out) {
  const int t = threadIdx.x, wave = t >> 6, lane = t & 63;
  const int row = blockIdx.x * 4 + wave;      // 0..32767
  const int b = row >> 12;
  const int i = row & (NPTS - 1);
  const float* xb  = x + (size_t)b * NPTS * 64;
  const float* sqb = sq + ((size_t)b << 12);

  const int n0 = gcnt[row * 4 + 0];
  const int n1 = gcnt[row * 4 + 1];
  const int n2 = gcnt[row * 4 + 2];
  const int n3 = gcnt[row * 4 + 3];
  if (n0 > QCAP || n1 > QCAP || n2 > QCAP || n3 > QCAP) return; // fb owns row

  const float sqi = sqb[i];
  float4 q[16];
#pragma unroll
  for (int c4 = 0; c4 < 16; ++c4)
    q[c4] = *(const float4*)(xb + (size_t)i * 64 + c4 * 4);

  const int n01  = n0 + n1;
  const int n012 = n01 + n2;
  const int n    = n012 + n3;                 // <= 384
  unsigned long long vk[6];
#pragma unroll
  for (int s = 0; s < 6; ++s) {
    int li = s * 64 + lane;
    unsigned long long v = 0xFFFFFFFFFFFULL;        // sentinel > any real
    if (li < n) {
      int sl = (li < n0)   ? li
             : (li < n01)  ? QCAP     + (li - n0)
             : (li < n012) ? 2 * QCAP + (li - n01)
                           : 3 * QCAP + (li - n012);
      int j = glist[(size_t)row * CAP + sl];
      const float4* xj = (const float4*)(xb + (size_t)j * 64);
      float dot = 0.f;
#pragma unroll
      for (int c4 = 0; c4 < 16; ++c4) {
        float4 c = xj[c4];
        dot = fmaf(q[c4].x, c.x, dot);
        dot = fmaf(q[c4].y, c.y, dot);
        dot = fmaf(q[c4].z, c.z, dot);
        dot = fmaf(q[c4].w, c.w, dot);
      }
      float d = fmaf(-2.f, dot, sqi + sqb[j]);
      unsigned u  = __float_as_uint(d);
      unsigned ck = (u & 0x80000000u) ? ~u : (u | 0x80000000u);
      v = ((unsigned long long)ck << 12) | (unsigned)j;
    }
    vk[s] = v;
  }
  // radix-select: prefix ends as the exact 32nd-smallest value (distinct)
  unsigned long long prefix = 0;
  int need = 32;
  for (int bit = 43; bit >= 0; --bit) {
    unsigned long long hm = (bit == 43) ? 0ULL
        : (~((1ULL << (bit + 1)) - 1ULL) & 0xFFFFFFFFFFFULL);
    int cnt0 = 0;
#pragma unroll
    for (int s = 0; s < 6; ++s) {
      bool a = ((vk[s] ^ prefix) & hm) == 0ULL;
      bool z = ((vk[s] >> bit) & 1ULL) == 0ULL;
      cnt0 += (int)__popcll(__ballot(a && z));
    }
    if (cnt0 < need) { need -= cnt0; prefix |= 1ULL << bit; }
  }
  int prev = 0;
#pragma unroll
  for (int s = 0; s < 6; ++s) {
    bool sel = vk[s] <= prefix;
    unsigned long long m = __ballot(sel);
    int rank = (int)__popcll(m & ((1ULL << lane) - 1ULL));
    if (sel)
      idx_out[(size_t)row * KNN + prev + rank] =
          (unsigned short)(vk[s] & 0xFFFULL);
    prev += (int)__popcll(m);
  }
}

// =====================================================================
// Rerank FALLBACK kernel (rare): early-exit on clean rows. Two-pass
// exact scan: per-lane min over own 64 cands -> 32-bit radix tau32 ->
// ballot-rank append survivors (cap 128) to LDS -> exact 44-bit lex
// radix-select. Tertiary: serial ballot-insert. Own kernel => own
// register budget: q[16] stays in VGPRs without constraining the main.
// =====================================================================
__global__ __launch_bounds__(256)
void knn_rerank_fb(const float* __restrict__ x, const float* __restrict__ sq,
                   const int* __restrict__ gcnt,
                   unsigned short* __restrict__ idx_out) {
  __shared__ unsigned long long fsurv[4][128];   // 4 KB, per-wave segments
  const int t = threadIdx.x, wave = t >> 6, lane = t & 63;
  const int row = blockIdx.x * 4 + wave;      // 0..32767
  const int b = row >> 12;
  const int i = row & (NPTS - 1);

  const int n0 = gcnt[row * 4 + 0];
  const int n1 = gcnt[row * 4 + 1];
  const int n2 = gcnt[row * 4 + 2];
  const int n3 = gcnt[row * 4 + 3];
  if (n0 <= QCAP && n1 <= QCAP && n2 <= QCAP && n3 <= QCAP) return;

  const float* xb  = x + (size_t)b * NPTS * 64;
  const float* sqb = sq + ((size_t)b << 12);
  const float sqi = sqb[i];

  float4 q[16];
#pragma unroll
  for (int c4 = 0; c4 < 16; ++c4)
    q[c4] = *(const float4*)(xb + (size_t)i * 64 + c4 * 4);

  // pass A: per-lane min of ck over own 64 candidates (j == lane mod 64)
  unsigned mnf = 0xFFFFFFFFu;
  for (int c0 = 0; c0 < NPTS; c0 += 64) {
    const int j = c0 + lane;
    const float4* xj = (const float4*)(xb + (size_t)j * 64);
    float dot = 0.f;
#pragma unroll
    for (int c4 = 0; c4 < 16; ++c4) {
      float4 c = xj[c4];
      dot = fmaf(q[c4].x, c.x, dot);
      dot = fmaf(q[c4].y, c.y, dot);
      dot = fmaf(q[c4].z, c.z, dot);
      dot = fmaf(q[c4].w, c.w, dot);
    }
    float d = fmaf(-2.f, dot, sqi + sqb[j]);
    unsigned u  = __float_as_uint(d);
    unsigned ck = (u & 0x80000000u) ? ~u : (u | 0x80000000u);
    mnf = ck < mnf ? ck : mnf;
  }
  // tau32 = exact 32nd-smallest of the 64 lane-mins
  unsigned tau32;
  {
    const unsigned v = mnf;
    unsigned prefix32 = 0;
    int need = 32;
    int act = 1;
    for (int bit = 31; bit >= 0; --bit) {
      const unsigned bv = (v >> bit) & 1u;
      unsigned long long m0 = __ballot(act && (bv == 0u));
      int c0n = (int)__popcll(m0);
      if (c0n >= need) {
        act = act && (bv == 0u);
      } else {
        need -= c0n;
        act = act && (bv == 1u);
        prefix32 |= (1u << bit);
      }
    }
    tau32 = prefix32;
  }
  // pass B: recompute, ballot-rank append survivors to LDS
  int cnt = 0;
  for (int c0 = 0; c0 < NPTS; c0 += 64) {
    const int j = c0 + lane;
    const float4* xj = (const float4*)(xb + (size_t)j * 64);
    float dot = 0.f;
#pragma unroll
    for (int c4 = 0; c4 < 16; ++c4) {
      float4 c = xj[c4];
      dot = fmaf(q[c4].x, c.x, dot);
      dot = fmaf(q[c4].y, c.y, dot);
      dot = fmaf(q[c4].z, c.z, dot);
      dot = fmaf(q[c4].w, c.w, dot);
    }
    float d = fmaf(-2.f, dot, sqi + sqb[j]);
    unsigned u  = __float_as_uint(d);
    unsigned ck = (u & 0x80000000u) ? ~u : (u | 0x80000000u);
    bool keep = ck <= tau32;
    unsigned long long mask = __ballot(keep);
    if (mask != 0ULL) {
      int rank = (int)__popcll(mask & ((1ULL << lane) - 1ULL));
      if (keep) {
        int pos = cnt + rank;
        if (pos < 128)
          fsurv[wave][pos] = ((unsigned long long)ck << 12) | (unsigned)j;
      }
      cnt += (int)__popcll(mask);
    }
  }
  if (cnt <= 128) {
    unsigned long long vk0 = (lane      < cnt) ? fsurv[wave][lane]      : 0xFFFFFFFFFFFULL;
    unsigned long long vk1 = (lane + 64 < cnt) ? fsurv[wave][lane + 64] : 0xFFFFFFFFFFFULL;
    unsigned long long prefix = 0;
    int need = 32;
    for (int bit = 43; bit >= 0; --bit) {
      unsigned long long hm = (bit == 43) ? 0ULL
          : (~((1ULL << (bit + 1)) - 1ULL) & 0xFFFFFFFFFFFULL);
      bool a0 = (((vk0 ^ prefix) & hm) == 0ULL) && (((vk0 >> bit) & 1ULL) == 0ULL);
      bool a1 = (((vk1 ^ prefix) & hm) == 0ULL) && (((vk1 >> bit) & 1ULL) == 0ULL);
      int cnt0 = (int)__popcll(__ballot(a0)) + (int)__popcll(__ballot(a1));
      if (cnt0 < need) { need -= cnt0; prefix |= 1ULL << bit; }
    }
    bool sel0 = vk0 <= prefix;
    unsigned long long m0 = __ballot(sel0);
    int rank0 = (int)__popcll(m0 & ((1ULL << lane) - 1ULL));
    if (sel0)
      idx_out[(size_t)row * KNN + rank0] = (unsigned short)(vk0 & 0xFFFULL);
    int prev = (int)__popcll(m0);
    bool sel1 = vk1 <= prefix;
    unsigned long long m1 = __ballot(sel1);
    int rank1 = (int)__popcll(m1 & ((1ULL << lane) - 1ULL));
    if (sel1)
      idx_out[(size_t)row * KNN + prev + rank1] = (unsigned short)(vk1 & 0xFFFULL);
  } else {
    // tertiary: exact full scan, validated serial ballot-insert
    unsigned long long ent = (0xFFFFFFFFFFFULL << 5) | (unsigned long long)(lane & 31);
    unsigned long long M   = (0xFFFFFFFFFFFULL << 5) | 31ULL;
    for (int c0 = 0; c0 < NPTS; c0 += 64) {
      const int j = c0 + lane;
      const float4* xj = (const float4*)(xb + (size_t)j * 64);
      float dot = 0.f;
#pragma unroll
      for (int c4 = 0; c4 < 16; ++c4) {
        float4 c = xj[c4];
        dot = fmaf(q[c4].x, c.x, dot);
        dot = fmaf(q[c4].y, c.y, dot);
        dot = fmaf(q[c4].z, c.z, dot);
        dot = fmaf(q[c4].w, c.w, dot);
      }
      float d = fmaf(-2.f, dot, sqi + sqb[j]);
      unsigned u  = __float_as_uint(d);
      unsigned ck = (u & 0x80000000u) ? ~u : (u | 0x80000000u);
      unsigned long long cq = ((unsigned long long)ck << 12) | (unsigned)j;
      unsigned long long mask = __ballot(cq < (M >> 5));
      while (mask) {
        const int src = __builtin_ctzll(mask);
        mask &= mask - 1;
        const unsigned long long bq = shfl_u64(cq, src);
        if (bq < (M >> 5)) {
          const unsigned slot = (unsigned)(M & 31ULL);
          if ((unsigned)(lane & 31) == slot) ent = (bq << 5) | slot;
          unsigned long long v = ent;
#pragma unroll
          for (int off = 16; off >= 1; off >>= 1) {
            unsigned long long w2 = shfl_xor_u64(v, off);
            v = (v > w2) ? v : w2;
          }
          M = v;
        }
      }
    }
    if (lane < 32)
      idx_out[(size_t)row * KNN + lane] =
          (unsigned short)((ent >> 5) & 0xFFFULL);
  }
}

// =====================================================================
// F=3 kNN: pass 1 (per-lane min + need=32 radix tau); pass 2 ballot-rank
// append of packed 44-bit keys to LDS (cap 128/row); exact lex radix-
// select. Overflow -> per-row exact full-scan fallback.
// =====================================================================
template <int F>
__global__ __launch_bounds__(256, 4) void knn_tiled(const float* __restrict__ x,
                                                    const float* __restrict__ sq,
                                                    unsigned short* __restrict__ idx_out) {
  constexpr int FP = 4;
  constexpr int TC = 256;
  constexpr int RPB = 32;
  constexpr int RPW = 8;
  constexpr int SCAP = 128;

  __shared__ __attribute__((aligned(16))) float qv[RPB][FP];
  __shared__ float qsq[RPB];
  __shared__ __attribute__((aligned(16))) float ct[TC][FP];
  __shared__ float csq[TC];
  __shared__ unsigned long long surv[RPB][SCAP];   // 32 KB

  const int t    = threadIdx.x;
  const int wave = t >> 6;
  const int lane = t & 63;
  const int rowbase = blockIdx.x << 5;
  const int b     = rowbase >> 12;
  const int ibase = rowbase & (NPTS - 1);
  const float* xb  = x + (size_t)b * NPTS * F;
  const float* sqb = sq + (b << 12);

  if (t < RPB) {
    qv[t][0] = xb[(size_t)(ibase + t) * 3 + 0];
    qv[t][1] = xb[(size_t)(ibase + t) * 3 + 1];
    qv[t][2] = xb[(size_t)(ibase + t) * 3 + 2];
    qv[t][3] = 0.f;
    qsq[t] = sqb[ibase + t];
  }
  __syncthreads();

  const int r0 = wave << 3;
  float4 q[RPW];
  float sqi[RPW];
#pragma unroll
  for (int rr = 0; rr < RPW; ++rr) {
    q[rr] = *reinterpret_cast<const float4*>(&qv[r0 + rr][0]);
    sqi[rr] = qsq[r0 + rr];
  }

  unsigned mn[RPW];
#pragma unroll
  for (int rr = 0; rr < RPW; ++rr) mn[rr] = 0xFFFFFFFFu;

  // ---------------- pass 1: per-lane min of ck ----------------
  for (int tile = 0; tile < NPTS / TC; ++tile) {
    __syncthreads();
    {
      int jg = tile * TC + t;
      ct[t][0] = xb[(size_t)jg * 3 + 0];
      ct[t][1] = xb[(size_t)jg * 3 + 1];
      ct[t][2] = xb[(size_t)jg * 3 + 2];
      ct[t][3] = 0.f;
      csq[t] = sqb[jg];
    }
    __syncthreads();

    float4 c0 = *reinterpret_cast<const float4*>(&ct[lane][0]);
    float4 c1 = *reinterpret_cast<const float4*>(&ct[lane + 64][0]);
    float4 c2 = *reinterpret_cast<const float4*>(&ct[lane + 128][0]);
    float4 c3 = *reinterpret_cast<const float4*>(&ct[lane + 192][0]);
    float cs[4];
#pragma unroll
    for (int s = 0; s < 4; ++s) cs[s] = csq[lane + 64 * s];

#pragma unroll
    for (int rr = 0; rr < RPW; ++rr) {
      float4 qq = q[rr];
      float dd[4];
      dd[0] = fmaf(qq.z, c0.z, fmaf(qq.y, c0.y, qq.x * c0.x));
      dd[1] = fmaf(qq.z, c1.z, fmaf(qq.y, c1.y, qq.x * c1.x));
      dd[2] = fmaf(qq.z, c2.z, fmaf(qq.y, c2.y, qq.x * c2.x));
      dd[3] = fmaf(qq.z, c3.z, fmaf(qq.y, c3.y, qq.x * c3.x));
#pragma unroll
      for (int s = 0; s < 4; ++s) {
        float d = fmaf(-2.f, dd[s], sqi[rr] + cs[s]);
        unsigned u  = __float_as_uint(d);
        unsigned ck = (u & 0x80000000u) ? ~u : (u | 0x80000000u);
        mn[rr] = ck < mn[rr] ? ck : mn[rr];
      }
    }
  }

  // tau[rr] = exact 32nd-smallest of the 64 lane-mins (radix over bits).
  unsigned tau[RPW];
#pragma unroll
  for (int rr = 0; rr < RPW; ++rr) {
    const unsigned v = mn[rr];
    unsigned prefix = 0;
    int need = 32;
    int act = 1;
    for (int bit = 31; bit >= 0; --bit) {
      const unsigned bv = (v >> bit) & 1u;
      unsigned long long m0 = __ballot(act && (bv == 0u));
      int c0n = (int)__popcll(m0);
      if (c0n >= need) {
        act = act && (bv == 0u);
      } else {
        need -= c0n;
        act = act && (bv == 1u);
        prefix |= (1u << bit);
      }
    }
    tau[rr] = prefix;
  }

  // ---------------- pass 2: ballot-rank append survivors ----------------
  int cnt[RPW];
#pragma unroll
  for (int rr = 0; rr < RPW; ++rr) cnt[rr] = 0;

  for (int tile = 0; tile < NPTS / TC; ++tile) {
    __syncthreads();
    {
      int jg = tile * TC + t;
      ct[t][0] = xb[(size_t)jg * 3 + 0];
      ct[t][1] = xb[(size_t)jg * 3 + 1];
      ct[t][2] = xb[(size_t)jg * 3 + 2];
      ct[t][3] = 0.f;
      csq[t] = sqb[jg];
    }
    __syncthreads();

    float4 c0 = *reinterpret_cast<const float4*>(&ct[lane][0]);
    float4 c1 = *reinterpret_cast<const float4*>(&ct[lane + 64][0]);
    float4 c2 = *reinterpret_cast<const float4*>(&ct[lane + 128][0]);
    float4 c3 = *reinterpret_cast<const float4*>(&ct[lane + 192][0]);
    float cs[4];
#pragma unroll
    for (int s = 0; s < 4; ++s) cs[s] = csq[lane + 64 * s];

#pragma unroll
    for (int rr = 0; rr < RPW; ++rr) {
      float4 qq = q[rr];
      float dd[4];
      dd[0] = fmaf(qq.z, c0.z, fmaf(qq.y, c0.y, qq.x * c0.x));
      dd[1] = fmaf(qq.z, c1.z, fmaf(qq.y, c1.y, qq.x * c1.x));
      dd[2] = fmaf(qq.z, c2.z, fmaf(qq.y, c2.y, qq.x * c2.x));
      dd[3] = fmaf(qq.z, c3.z, fmaf(qq.y, c3.y, qq.x * c3.x));
#pragma unroll
      for (int s = 0; s < 4; ++s) {
        float d = fmaf(-2.f, dd[s], sqi[rr] + cs[s]);
        unsigned u  = __float_as_uint(d);
        unsigned ck = (u & 0x80000000u) ? ~u : (u | 0x80000000u);
        bool keep = ck <= tau[rr];
        unsigned long long mask = __ballot(keep);
        if (mask != 0ULL) {
          int rank = (int)__popcll(mask & ((1ULL << lane) - 1ULL));
          if (keep) {
            int pos = cnt[rr] + rank;
            if (pos < SCAP)
              surv[r0 + rr][pos] =
                  ((unsigned long long)ck << 12) |
                  (unsigned)(tile * TC + s * 64 + lane);
          }
          cnt[rr] += (int)__popcll(mask);
        }
      }
    }
  }

  // ---------------- exact lex top-32 per row via radix-select ----------------
#pragma unroll
  for (int rr = 0; rr < RPW; ++rr) {
    const int row = rowbase + r0 + rr;
    const int n = cnt[rr];
    if (n <= SCAP) {
      unsigned long long vk0 = (lane      < n) ? surv[r0 + rr][lane]      : 0xFFFFFFFFFFFULL;
      unsigned long long vk1 = (lane + 64 < n) ? surv[r0 + rr][lane + 64] : 0xFFFFFFFFFFFULL;
      unsigned long long prefix = 0;
      int need = 32;
      for (int bit = 43; bit >= 0; --bit) {
        unsigned long long hm = (bit == 43) ? 0ULL
            : (~((1ULL << (bit + 1)) - 1ULL) & 0xFFFFFFFFFFFULL);
        bool a0 = (((vk0 ^ prefix) & hm) == 0ULL) && (((vk0 >> bit) & 1ULL) == 0ULL);
        bool a1 = (((vk1 ^ prefix) & hm) == 0ULL) && (((vk1 >> bit) & 1ULL) == 0ULL);
        int cnt0 = (int)__popcll(__ballot(a0)) + (int)__popcll(__ballot(a1));
        if (cnt0 < need) { need -= cnt0; prefix |= 1ULL << bit; }
      }
      bool sel0 = vk0 <= prefix;
      unsigned long long m0 = __ballot(sel0);
      int rank0 = (int)__popcll(m0 & ((1ULL << lane) - 1ULL));
      if (sel0)
        idx_out[(row << 5) + rank0] = (unsigned short)(vk0 & 0xFFFULL);
      int prev = (int)__popcll(m0);
      bool sel1 = vk1 <= prefix;
      unsigned long long m1 = __ballot(sel1);
      int rank1 = (int)__popcll(m1 & ((1ULL << lane) - 1ULL));
      if (sel1)
        idx_out[(row << 5) + prev + rank1] = (unsigned short)(vk1 & 0xFFFULL);
    } else {
      // overflow fallback: exact full scan with validated ballot-insert
      unsigned long long ent = (0xFFFFFFFFFFFULL << 5) | (unsigned long long)(lane & 31);
      unsigned long long M   = (0xFFFFFFFFFFFULL << 5) | 31ULL;
      const float4 qq = q[rr];
      const float si = sqi[rr];
      for (int c0i = 0; c0i < NPTS; c0i += 64) {
        const int j = c0i + lane;
        const float dd_ = fmaf(qq.z, xb[(size_t)j * 3 + 2],
                           fmaf(qq.y, xb[(size_t)j * 3 + 1],
                                qq.x * xb[(size_t)j * 3 + 0]));
        float d = fmaf(-2.f, dd_, si + sqb[j]);
        unsigned u  = __float_as_uint(d);
        unsigned ck = (u & 0x80000000u) ? ~u : (u | 0x80000000u);
        unsigned long long cq = ((unsigned long long)ck << 12) | (unsigned)j;
        unsigned long long mask = __ballot(cq < (M >> 5));
        while (mask) {
          const int src = __builtin_ctzll(mask);
          mask &= mask - 1;
          const unsigned long long bq = shfl_u64(cq, src);
          if (bq < (M >> 5)) {
            const unsigned slot = (unsigned)(M & 31ULL);
            if ((unsigned)(lane & 31) == slot) ent = (bq << 5) | slot;
            unsigned long long v = ent;
#pragma unroll
            for (int off = 16; off >= 1; off >>= 1) {
              unsigned long long w2 = shfl_xor_u64(v, off);
              v = (v > w2) ? v : w2;
            }
            M = v;
          }
        }
      }
      if (lane < 32)
        idx_out[(row << 5) + lane] = (unsigned short)((ent >> 5) & 0xFFFULL);
    }
  }
}

// ---------------- per-node P = x.Wbot ; C = x.(Wtop-Wbot) + b ----------------
__global__ __launch_bounds__(256) void mlp_pc_kernel(const float* __restrict__ xin,
                                                     const float* __restrict__ W,
                                                     const float* __restrict__ bias,
                                                     float* __restrict__ P,
                                                     float* C,
                                                     int F, int O, int total) {
  int t = blockIdx.x * 256 + threadIdx.x;
  if (t >= total) return;
  int n = t / O, o = t % O;
  const float* xr = xin + (size_t)n * F;
  const float* Wt = W + o;
  const float* Wb = W + (size_t)F * O + o;
  float p = 0.f, c = 0.f;
  for (int f = 0; f < F; ++f) {
    float a  = xr[f];
    float wt = Wt[(size_t)f * O];
    float wb = Wb[(size_t)f * O];
    p = fmaf(a, wb, p);
    c = fmaf(a, wt - wb, c);
  }
  P[t] = p;
  C[t] = c + bias[o];
}

// ---------------- h[t] (pre-filled with C) += max_k P[idx_k] ----------------
__global__ __launch_bounds__(256) void aggregate_kernel(const unsigned short* __restrict__ idx,
                                                        const float* __restrict__ P,
                                                        float* h, int O, int total) {
  int t = blockIdx.x * 256 + threadIdx.x;
  if (t >= total) return;
  int n = t / O, o = t % O;
  const unsigned short* ix = idx + (size_t)n * KNN;
  const int rowbase = (n >> 12) << 12;
  float m = -3.402823466e+38f;
  for (int k = 0; k < KNN; ++k) {
    int jg = rowbase + ix[k];
    float v = P[(size_t)jg * O + o];
    m = fmaxf(m, v);
  }
  h[t] = h[t] + m;
}

// ---------------- BN stats over relu(h): mean + invstd per channel ----------
__global__ __launch_bounds__(256) void bn_stats_kernel(const float* __restrict__ h,
                                                       float* __restrict__ stats) {
  const int c = blockIdx.x;
  const int t = threadIdx.x;
  double s = 0.0, s2 = 0.0;
  for (int n = t; n < NROWS; n += 256) {
    float v = h[(size_t)n * 64 + c];
    v = v > 0.f ? v : 0.f;
    s += v;
    s2 += (double)v * v;
  }
  __shared__ double ls[256], ls2[256];
  ls[t] = s; ls2[t] = s2;
  __syncthreads();
  for (int st = 128; st; st >>= 1) {
    if (t < st) { ls[t] += ls[t + st]; ls2[t] += ls2[t + st]; }
    __syncthreads();
  }
  if (t == 0) {
    double mean = ls[0] / (double)NROWS;
    double var  = ls2[0] / (double)NROWS - mean * mean;
    stats[c]      = (float)mean;
    stats[64 + c] = (float)(1.0 / sqrt(var + 1e-5));
  }
}

// ---------------- apply: out = (relu(h)-mean)*invstd*g + be ----------------
__global__ __launch_bounds__(256) void bn_apply_kernel(const float* h,
                                                       const float* __restrict__ stats,
                                                       const float* __restrict__ g,
                                                       const float* __restrict__ be,
                                                       float* out, int total) {
  int t = blockIdx.x * 256 + threadIdx.x;
  if (t >= total) return;
  int ch = t & 63;
  float v = fmaxf(h[t], 0.f);
  out[t] = (v - stats[ch]) * stats[64 + ch] * g[ch] + be[ch];
}

// ---------------- write h3 to out + per-block loss partials ----------------
__global__ __launch_bounds__(256) void final_kernel(const float* __restrict__ h3,
                                                    const float* __restrict__ target,
                                                    float* __restrict__ out,
                                                    double* __restrict__ partial) {
  double s = 0.0;
  for (int t = blockIdx.x * 256 + threadIdx.x; t < NROWS * 3; t += 256 * 256) {
    float v = h3[t];
    out[t] = v;
    float d = v - target[t];
    s += (double)d * d;
  }
  __shared__ double ls[256];
  int t = threadIdx.x;
  ls[t] = s;
  __syncthreads();
  for (int st = 128; st; st >>= 1) {
    if (t < st) ls[t] += ls[t + st];
    __syncthreads();
  }
  if (t == 0) partial[blockIdx.x] = ls[0];
}

__global__ __launch_bounds__(256) void loss_kernel(const double* __restrict__ partial,
                                                   float* __restrict__ out) {
  int t = threadIdx.x;
  __shared__ double ls[256];
  ls[t] = partial[t];
  __syncthreads();
  for (int st = 128; st; st >>= 1) {
    if (t < st) ls[t] += ls[t + st];
    __syncthreads();
  }
  if (t == 0) out[NROWS * 3] = (float)(ls[0] / (double)(NROWS * 3));
}

// ---------------- driver ----------------
extern "C" void kernel_launch(void* const* d_in, const int* in_sizes, int n_in,
                              void* d_out, int out_size, void* d_ws, size_t ws_size,
                              hipStream_t stream) {
  const float* x   = (const float*)d_in[0];
  const float* tgt = (const float*)d_in[1];
  const float* W1  = (const float*)d_in[2];
  const float* b1  = (const float*)d_in[3];
  const float* g1  = (const float*)d_in[4];
  const float* be1 = (const float*)d_in[5];
  const float* W2  = (const float*)d_in[6];
  const float* b2  = (const float*)d_in[7];
  const float* g2  = (const float*)d_in[8];
  const float* be2 = (const float*)d_in[9];
  const float* W3  = (const float*)d_in[10];
  const float* b3  = (const float*)d_in[11];
  float* out = (float*)d_out;

  char* ws = (char*)d_ws;
  size_t off = 0;
  float* sq    = (float*)(ws + off); off += (size_t)NROWS * 4;           // 128 KB
  unsigned short* idxb = (unsigned short*)(ws + off); off += (size_t)NROWS * KNN * 2; // 2 MB
  float* P     = (float*)(ws + off); off += (size_t)NROWS * 64 * 4;      // 8 MB
  float* CA    = (float*)(ws + off); off += (size_t)NROWS * 64 * 4;      // 8 MB
  float* CB    = (float*)(ws + off); off += (size_t)NROWS * 64 * 4;      // 8 MB
  int*   gcnt  = (int*)(ws + off);   off += (size_t)NROWS * 16;          // 512 KB (4 quarters)
  unsigned short* glist = (unsigned short*)(ws + off); off += (size_t)NROWS * CAP * 2; // 25.2 MB
  float* stats = (float*)(ws + off); off += 256 * 4;
  float* sqmax = (float*)(ws + off); off += 64;
  double* part = (double*)(ws + off); off += 256 * 8;

  // hi/lo (bf16 frag-major, 4 MB each) alias P (8 MB): P is dead during screen/rerank.
  unsigned short* hib = (unsigned short*)P;
  unsigned short* lob = hib + (size_t)NROWS * 64;

  const int T64 = NROWS * 64;
  const int T3  = NROWS * 3;

  // ---- layer 1 (F=3 -> 64), VALU kNN ----
  sqnorm_kernel<<<NROWS / 256, 256, 0, stream>>>(x, sq, 3);
  knn_tiled<3><<<NROWS / 32, 256, 0, stream>>>(x, sq, idxb);
  mlp_pc_kernel<<<T64 / 256, 256, 0, stream>>>(x, W1, b1, P, CA, 3, 64, T64);
  aggregate_kernel<<<T64 / 256, 256, 0, stream>>>(idxb, P, CA, 64, T64);
  bn_stats_kernel<<<64, 256, 0, stream>>>(CA, stats);
  bn_apply_kernel<<<T64 / 256, 256, 0, stream>>>(CA, stats, g1, be1, CA, T64);

  // ---- layer 2 (F=64 -> 64), MFMA screen + exact rerank ----
  sqnorm_kernel<<<NROWS / 256, 256, 0, stream>>>(CA, sq, 64);
  split_kernel<<<T64 / 256, 256, 0, stream>>>(CA, hib, lob, T64);
  batchmax_kernel<<<NB, 256, 0, stream>>>(sq, sqmax);
  knn_screen<<<2048, 256, 0, stream>>>(hib, lob, sq, sqmax, gcnt, glist);
  knn_rerank<<<NROWS / 4, 256, 0, stream>>>(CA, sq, gcnt, glist, idxb);
  knn_rerank_fb<<<NROWS / 4, 256, 0, stream>>>(CA, sq, gcnt, idxb);
  mlp_pc_kernel<<<T64 / 256, 256, 0, stream>>>(CA, W2, b2, P, CB, 64, 64, T64);
  aggregate_kernel<<<T64 / 256, 256, 0, stream>>>(idxb, P, CB, 64, T64);
  bn_stats_kernel<<<64, 256, 0, stream>>>(CB, stats);
  bn_apply_kernel<<<T64 / 256, 256, 0, stream>>>(CB, stats, g2, be2, CB, T64);

  // ---- layer 3 (F=64 -> 3), MFMA screen + exact rerank ----
  sqnorm_kernel<<<NROWS / 256, 256, 0, stream>>>(CB, sq, 64);
  split_kernel<<<T64 / 256, 256, 0, stream>>>(CB, hib, lob, T64);
  batchmax_kernel<<<NB, 256, 0, stream>>>(sq, sqmax);
  knn_screen<<<2048, 256, 0, stream>>>(hib, lob, sq, sqmax, gcnt, glist);
  knn_rerank<<<NROWS / 4, 256, 0, stream>>>(CB, sq, gcnt, glist, idxb);
  knn_rerank_fb<<<NROWS / 4, 256, 0, stream>>>(CB, sq, gcnt, idxb);
  mlp_pc_kernel<<<T3 / 256, 256, 0, stream>>>(CB, W3, b3, P, CA, 64, 3, T3);
  aggregate_kernel<<<T3 / 256, 256, 0, stream>>>(idxb, P, CA, 3, T3);

  // ---- output + loss ----
  final_kernel<<<256, 256, 0, stream>>>(CA, tgt, out, part);
  loss_kernel<<<1, 256, 0, stream>>>(part, out);
}

// Round 9
// 1252.650 us; speedup vs baseline: 1.6160x; 1.1796x over previous
//
#include <hip/hip_runtime.h>
#include <cstdint>
#include <cstddef>

static constexpr int NPTS  = 4096;
static constexpr int NB    = 8;
static constexpr int NROWS = NB * NPTS;      // 32768
static constexpr int KNN   = 32;
static constexpr int CAP   = 256;            // survivor list capacity per row (2 halves)
static constexpr int HCAP  = 128;            // per candidate-half capacity

typedef __attribute__((ext_vector_type(8))) short  bf16x8;
typedef __attribute__((ext_vector_type(4))) float  f32x4;

// ---------------- utility: 64-bit shuffles built from 32-bit ----------------
__device__ __forceinline__ unsigned long long shfl_xor_u64(unsigned long long v, int m) {
  int lo = __shfl_xor((int)(unsigned)(v & 0xFFFFFFFFULL), m, 64);
  int hi = __shfl_xor((int)(unsigned)(v >> 32), m, 64);
  return ((unsigned long long)(unsigned)hi << 32) | (unsigned)lo;
}
__device__ __forceinline__ unsigned long long shfl_u64(unsigned long long v, int src) {
  int lo = __shfl((int)(unsigned)(v & 0xFFFFFFFFULL), src, 64);
  int hi = __shfl((int)(unsigned)(v >> 32), src, 64);
  return ((unsigned long long)(unsigned)hi << 32) | (unsigned)lo;
}

// order-preserving float<->unsigned maps (for radix select over floats)
__device__ __forceinline__ unsigned f2o(float f) {
  unsigned u = __float_as_uint(f);
  return (u & 0x80000000u) ? ~u : (u | 0x80000000u);
}
__device__ __forceinline__ float o2f(unsigned o) {
  unsigned u = (o & 0x80000000u) ? (o ^ 0x80000000u) : ~o;
  return __uint_as_float(u);
}

// ---------------- squared norms per point ----------------
__global__ __launch_bounds__(256) void sqnorm_kernel(const float* __restrict__ x,
                                                     float* __restrict__ sq, int F) {
  int t = blockIdx.x * 256 + threadIdx.x;
  if (t >= NROWS) return;
  const float* p = x + (size_t)t * F;
  float s = 0.f;
  for (int f = 0; f < F; ++f) s = fmaf(p[f], p[f], s);
  sq[t] = s;
}

// =====================================================================
// split fp32 -> bf16 hi + lo (RNE), written in MFMA-FRAGMENT-MAJOR
// layout (R8-validated): for batch b, 16-cand tile g, piece p (feats
// p*32..), chunk index (quad*16 + l16) holds cand (g*16+l16), feats
// p*32+quad*8..+8. Screen loads every A/B fragment as base + lane*16B:
// one fully-coalesced 1KB transaction (R7's row-major direct loads
// were 128B-stride gathers -> 515us; R8 frag-major -> 238us).
// =====================================================================
__global__ __launch_bounds__(256) void split_kernel(const float* __restrict__ x,
                                                    unsigned short* __restrict__ hi,
                                                    unsigned short* __restrict__ lo,
                                                    int total) {
  int t = blockIdx.x * 256 + threadIdx.x;
  if (t >= total) return;
  float v = x[t];
  unsigned u = __float_as_uint(v);
  unsigned h = (u + 0x7FFFu + ((u >> 16) & 1u)) >> 16;
  float hf = __uint_as_float(h << 16);
  float r = v - hf;
  unsigned ur = __float_as_uint(r);
  unsigned l = (ur + 0x7FFFu + ((ur >> 16) & 1u)) >> 16;

  const int n = t >> 6;            // row
  const int f = t & 63;            // feature
  const int b   = n >> 12;
  const int g   = (n >> 4) & 255;  // 16-row tile within batch
  const int l16 = n & 15;
  const int p    = f >> 5;         // piece (feats 0-31 / 32-63)
  const int quad = (f >> 3) & 3;
  const int w    = f & 7;
  const size_t dst = ((((size_t)b * 256 + g) * 2 + p) << 9)   // tile-piece base (512 shorts)
                   + (size_t)(quad * 16 + l16) * 8 + w;
  hi[dst] = (unsigned short)h;
  lo[dst] = (unsigned short)l;
}

// ---------------- per-batch max of sq ----------------
__global__ __launch_bounds__(256) void batchmax_kernel(const float* __restrict__ sq,
                                                       float* __restrict__ sqmax) {
  int b = blockIdx.x, t = threadIdx.x;
  float m = 0.f;
  for (int i = t; i < NPTS; i += 256) m = fmaxf(m, sq[b * NPTS + i]);
  for (int off = 32; off >= 1; off >>= 1) m = fmaxf(m, __shfl_xor(m, off, 64));
  __shared__ float ls[4];
  if ((t & 63) == 0) ls[t >> 6] = m;
  __syncthreads();
  if (t == 0) sqmax[b] = fmaxf(fmaxf(ls[0], ls[1]), fmaxf(ls[2], ls[3]));
}

// =====================================================================
// Screen (F=64), R9 = R8 data path x R6 split statistics. No LDS, no
// barriers; fragment-major coalesced global loads (L2-resident 512KB
// half-slab shared by 64 rowgroup-blocks). Grid 1024 = 8 batches x
// 64 rowgroups x 2 cand-halves; block owns 64 rows (4 waves x 16),
// scans 2048 cands (128 MFMA subs). Per-half T = exact 32nd-smallest
// of the quad's 64-value union (16 lanes x streaming top-4),
// radix-select over quad ballot slices (R6-validated: HCAP=128 held
// with negligible fb). Soundness: >=32 half cands <= T => overall
// exact 32nd <= T+eps => every exact lex top-32 member in half h has
// d_approx <= T+2eps -> admitted by its own half. Survivors to
// per-half glist segments (2 x 128), quad-ballot rank.
// R8 lesson kept: launch_bounds (256,4) so VGPR stays ~52 (no spill)
// while the compiler can pipeline loads across subs.
// =====================================================================
__global__ __launch_bounds__(256, 4)
void knn_screen(const unsigned short* __restrict__ hi,
                const unsigned short* __restrict__ lo,
                const float* __restrict__ sq,
                const float* __restrict__ sqmax,
                int* __restrict__ gcnt,
                unsigned short* __restrict__ glist) {
  const int t = threadIdx.x, wave = t >> 6, lane = t & 63;
  const int l16 = lane & 15, quad = lane >> 4;
  const int bid = blockIdx.x;
  const int b    = bid & 7;                         // XCD-affine batch
  const int half = (bid >> 3) & 1;                  // candidate half
  const int i0w  = ((bid >> 4) << 6) + (wave << 4); // this wave's 16 rows
  const int cbh  = half << 11;                      // candidate base (rows)
  const size_t base = (size_t)b * NPTS;
  const unsigned short* hib = hi + base * 64;       // batch frag base
  const unsigned short* lob = lo + base * 64;
  const float* sqb = sq + base;
  const float sqm = sqmax[b];
  const int laneoff = lane * 8;

  // A fragments: tile g_A = i0w>>4, piece kb -> coalesced 1KB loads
  bf16x8 ahi[2], alo[2];
#pragma unroll
  for (int kb = 0; kb < 2; ++kb) {
    const size_t abase = ((size_t)((i0w >> 4) * 2 + kb) << 9);
    ahi[kb] = *(const bf16x8*)(hib + abase + laneoff);
    alo[kb] = *(const bf16x8*)(lob + abase + laneoff);
  }
  float sqi4[4];
#pragma unroll
  for (int reg = 0; reg < 4; ++reg) sqi4[reg] = sqb[i0w + quad * 4 + reg];

  float t1[4], t2[4], t3[4], t4[4], tinf4[4];
  int cnt4[4] = {0, 0, 0, 0};
#pragma unroll
  for (int reg = 0; reg < 4; ++reg) {
    t1[reg] = 3.4e38f; t2[reg] = 3.4e38f; t3[reg] = 3.4e38f; t4[reg] = 3.4e38f;
    tinf4[reg] = 0.f;
  }

  // ---------------- pass 0: streaming top-4 per (lane,reg) ----------------
#pragma unroll 2
  for (int sub = 0; sub < 128; ++sub) {
    const size_t bb = ((size_t)((half * 128 + sub) * 2) << 9);
    bf16x8 bh0 = *(const bf16x8*)(hib + bb + laneoff);
    bf16x8 bh1 = *(const bf16x8*)(hib + bb + 512 + laneoff);
    bf16x8 bl0 = *(const bf16x8*)(lob + bb + laneoff);
    bf16x8 bl1 = *(const bf16x8*)(lob + bb + 512 + laneoff);
    f32x4 acc = {0.f, 0.f, 0.f, 0.f};
    acc = __builtin_amdgcn_mfma_f32_16x16x32_bf16(ahi[0], bh0, acc, 0, 0, 0);
    acc = __builtin_amdgcn_mfma_f32_16x16x32_bf16(ahi[1], bh1, acc, 0, 0, 0);
    acc = __builtin_amdgcn_mfma_f32_16x16x32_bf16(ahi[0], bl0, acc, 0, 0, 0);
    acc = __builtin_amdgcn_mfma_f32_16x16x32_bf16(ahi[1], bl1, acc, 0, 0, 0);
    acc = __builtin_amdgcn_mfma_f32_16x16x32_bf16(alo[0], bh0, acc, 0, 0, 0);
    acc = __builtin_amdgcn_mfma_f32_16x16x32_bf16(alo[1], bh1, acc, 0, 0, 0);
    const float cs = sqb[cbh + sub * 16 + l16];
#pragma unroll
    for (int reg = 0; reg < 4; ++reg) {   // C/D: col=l16, row=quad*4+reg
      float d = fmaf(-2.f, acc[reg], sqi4[reg] + cs);
      // sorted top-4 insert (sorting network)
      float m1 = fminf(d,  t1[reg]); float M1 = fmaxf(d,  t1[reg]);
      float m2 = fminf(M1, t2[reg]); float M2 = fmaxf(M1, t2[reg]);
      float m3 = fminf(M2, t3[reg]); float M3 = fmaxf(M2, t3[reg]);
      t1[reg] = m1; t2[reg] = m2; t3[reg] = m3;
      t4[reg] = fminf(M3, t4[reg]);
    }
  }

  // T = exact 32nd-smallest of the quad's 64 values (16 lanes x top-4)
#pragma unroll
  for (int reg = 0; reg < 4; ++reg) {
    unsigned c0s = f2o(t1[reg]);
    unsigned c1s = f2o(t2[reg]);
    unsigned c2s = f2o(t3[reg]);
    unsigned c3s = f2o(t4[reg]);
    unsigned prefix = 0;
    int need = 32;
    for (int bit = 31; bit >= 0; --bit) {
      unsigned hm = (bit == 31) ? 0u : ~((1u << (bit + 1)) - 1u);
      bool a0 = (((c0s ^ prefix) & hm) == 0u) && (((c0s >> bit) & 1u) == 0u);
      bool a1 = (((c1s ^ prefix) & hm) == 0u) && (((c1s >> bit) & 1u) == 0u);
      bool a2 = (((c2s ^ prefix) & hm) == 0u) && (((c2s >> bit) & 1u) == 0u);
      bool a3 = (((c3s ^ prefix) & hm) == 0u) && (((c3s >> bit) & 1u) == 0u);
      unsigned long long b0 = __ballot(a0);
      unsigned long long b1 = __ballot(a1);
      unsigned long long b2 = __ballot(a2);
      unsigned long long b3 = __ballot(a3);
      int cnt0 = __popc((unsigned)((b0 >> (quad * 16)) & 0xFFFFULL))
               + __popc((unsigned)((b1 >> (quad * 16)) & 0xFFFFULL))
               + __popc((unsigned)((b2 >> (quad * 16)) & 0xFFFFULL))
               + __popc((unsigned)((b3 >> (quad * 16)) & 0xFFFFULL));
      if (cnt0 < need) { need -= cnt0; prefix |= 1u << bit; }
    }
    float T = o2f(prefix);
    float eps = 6e-5f * (sqi4[reg] + sqm) + 1e-5f;
    tinf4[reg] = T + 2.f * eps;
  }

  // ---------------- pass 1: recompute, ballot-rank append ----------------
#pragma unroll 2
  for (int sub = 0; sub < 128; ++sub) {
    const size_t bb = ((size_t)((half * 128 + sub) * 2) << 9);
    bf16x8 bh0 = *(const bf16x8*)(hib + bb + laneoff);
    bf16x8 bh1 = *(const bf16x8*)(hib + bb + 512 + laneoff);
    bf16x8 bl0 = *(const bf16x8*)(lob + bb + laneoff);
    bf16x8 bl1 = *(const bf16x8*)(lob + bb + 512 + laneoff);
    f32x4 acc = {0.f, 0.f, 0.f, 0.f};
    acc = __builtin_amdgcn_mfma_f32_16x16x32_bf16(ahi[0], bh0, acc, 0, 0, 0);
    acc = __builtin_amdgcn_mfma_f32_16x16x32_bf16(ahi[1], bh1, acc, 0, 0, 0);
    acc = __builtin_amdgcn_mfma_f32_16x16x32_bf16(ahi[0], bl0, acc, 0, 0, 0);
    acc = __builtin_amdgcn_mfma_f32_16x16x32_bf16(ahi[1], bl1, acc, 0, 0, 0);
    acc = __builtin_amdgcn_mfma_f32_16x16x32_bf16(alo[0], bh0, acc, 0, 0, 0);
    acc = __builtin_amdgcn_mfma_f32_16x16x32_bf16(alo[1], bh1, acc, 0, 0, 0);
    const int jg0 = cbh + sub * 16 + l16;
    const float cs = sqb[jg0];
#pragma unroll
    for (int reg = 0; reg < 4; ++reg) {
      float d = fmaf(-2.f, acc[reg], sqi4[reg] + cs);
      bool keep = d <= tinf4[reg];
      unsigned long long mask = __ballot(keep);
      unsigned qm = (unsigned)((mask >> (quad * 16)) & 0xFFFFULL);
      if (qm) {
        int rank = __popc(qm & ((1u << l16) - 1u));
        if (keep) {
          int pos = cnt4[reg] + rank;
          if (pos < HCAP)
            glist[(size_t)(base + i0w + quad * 4 + reg) * CAP + half * HCAP + pos] =
                (unsigned short)jg0;
        }
        cnt4[reg] += __popc(qm);
      }
    }
  }

  if (l16 == 0) {
#pragma unroll
    for (int reg = 0; reg < 4; ++reg)
      gcnt[(base + i0w + quad * 4 + reg) * 2 + half] = cnt4[reg];
  }
}

// =====================================================================
// Rerank MAIN path (R5/R6-validated, spill-free). One wave per row;
// exact fp32 distances (bit-identical ascending c4 fma chain) on
// survivors from both half-segments; exact lex-(dist,idx) top-32 SET
// via 44-bit radix-select. Overflow rows -> knn_rerank_fb.
// =====================================================================
__global__ __launch_bounds__(256, 2)
void knn_rerank(const float* __restrict__ x, const float* __restrict__ sq,
                const int* __restrict__ gcnt,
                const unsigned short* __restrict__ glist,
                unsigned short* __restrict__ idx_out) {
  const int t = threadIdx.x, wave = t >> 6, lane = t & 63;
  const int row = blockIdx.x * 4 + wave;      // 0..32767
  const int b = row >> 12;
  const int i = row & (NPTS - 1);
  const float* xb  = x + (size_t)b * NPTS * 64;
  const float* sqb = sq + ((size_t)b << 12);

  const int n0 = gcnt[row * 2];
  const int n1 = gcnt[row * 2 + 1];
  if (n0 > HCAP || n1 > HCAP) return;         // fb kernel owns this row

  const float sqi = sqb[i];
  float4 q[16];
#pragma unroll
  for (int c4 = 0; c4 < 16; ++c4)
    q[c4] = *(const float4*)(xb + (size_t)i * 64 + c4 * 4);

  const int n = n0 + n1;                      // <= 256
  unsigned long long vk[4];
#pragma unroll
  for (int s = 0; s < 4; ++s) {
    int li = s * 64 + lane;
    unsigned long long v = 0xFFFFFFFFFFFULL;        // sentinel > any real
    if (li < n) {
      int sl = (li < n0) ? li : (HCAP + (li - n0));
      int j = glist[(size_t)row * CAP + sl];
      const float4* xj = (const float4*)(xb + (size_t)j * 64);
      float dot = 0.f;
#pragma unroll
      for (int c4 = 0; c4 < 16; ++c4) {
        float4 c = xj[c4];
        dot = fmaf(q[c4].x, c.x, dot);
        dot = fmaf(q[c4].y, c.y, dot);
        dot = fmaf(q[c4].z, c.z, dot);
        dot = fmaf(q[c4].w, c.w, dot);
      }
      float d = fmaf(-2.f, dot, sqi + sqb[j]);
      unsigned u  = __float_as_uint(d);
      unsigned ck = (u & 0x80000000u) ? ~u : (u | 0x80000000u);
      v = ((unsigned long long)ck << 12) | (unsigned)j;
    }
    vk[s] = v;
  }
  // radix-select: prefix ends as the exact 32nd-smallest value (distinct)
  unsigned long long prefix = 0;
  int need = 32;
  for (int bit = 43; bit >= 0; --bit) {
    unsigned long long hm = (bit == 43) ? 0ULL
        : (~((1ULL << (bit + 1)) - 1ULL) & 0xFFFFFFFFFFFULL);
    int cnt0 = 0;
#pragma unroll
    for (int s = 0; s < 4; ++s) {
      bool a = ((vk[s] ^ prefix) & hm) == 0ULL;
      bool z = ((vk[s] >> bit) & 1ULL) == 0ULL;
      cnt0 += (int)__popcll(__ballot(a && z));
    }
    if (cnt0 < need) { need -= cnt0; prefix |= 1ULL << bit; }
  }
  int prev = 0;
#pragma unroll
  for (int s = 0; s < 4; ++s) {
    bool sel = vk[s] <= prefix;
    unsigned long long m = __ballot(sel);
    int rank = (int)__popcll(m & ((1ULL << lane) - 1ULL));
    if (sel)
      idx_out[(size_t)row * KNN + prev + rank] =
          (unsigned short)(vk[s] & 0xFFFULL);
    prev += (int)__popcll(m);
  }
}

// =====================================================================
// Rerank FALLBACK kernel (rare; R6-validated): early-exit on clean
// rows. Two-pass exact scan: per-lane min over own 64 cands -> 32-bit
// radix tau32 -> ballot-rank append survivors (cap 128) to LDS ->
// exact 44-bit lex radix-select. Tertiary: serial ballot-insert.
// =====================================================================
__global__ __launch_bounds__(256)
void knn_rerank_fb(const float* __restrict__ x, const float* __restrict__ sq,
                   const int* __restrict__ gcnt,
                   unsigned short* __restrict__ idx_out) {
  __shared__ unsigned long long fsurv[4][128];   // 4 KB, per-wave segments
  const int t = threadIdx.x, wave = t >> 6, lane = t & 63;
  const int row = blockIdx.x * 4 + wave;      // 0..32767
  const int b = row >> 12;
  const int i = row & (NPTS - 1);

  const int n0 = gcnt[row * 2];
  const int n1 = gcnt[row * 2 + 1];
  if (n0 <= HCAP && n1 <= HCAP) return;       // main kernel handled it

  const float* xb  = x + (size_t)b * NPTS * 64;
  const float* sqb = sq + ((size_t)b << 12);
  const float sqi = sqb[i];

  float4 q[16];
#pragma unroll
  for (int c4 = 0; c4 < 16; ++c4)
    q[c4] = *(const float4*)(xb + (size_t)i * 64 + c4 * 4);

  // pass A: per-lane min of ck over own 64 candidates (j == lane mod 64)
  unsigned mnf = 0xFFFFFFFFu;
  for (int c0 = 0; c0 < NPTS; c0 += 64) {
    const int j = c0 + lane;
    const float4* xj = (const float4*)(xb + (size_t)j * 64);
    float dot = 0.f;
#pragma unroll
    for (int c4 = 0; c4 < 16; ++c4) {
      float4 c = xj[c4];
      dot = fmaf(q[c4].x, c.x, dot);
      dot = fmaf(q[c4].y, c.y, dot);
      dot = fmaf(q[c4].z, c.z, dot);
      dot = fmaf(q[c4].w, c.w, dot);
    }
    float d = fmaf(-2.f, dot, sqi + sqb[j]);
    unsigned u  = __float_as_uint(d);
    unsigned ck = (u & 0x80000000u) ? ~u : (u | 0x80000000u);
    mnf = ck < mnf ? ck : mnf;
  }
  // tau32 = exact 32nd-smallest of the 64 lane-mins
  unsigned tau32;
  {
    const unsigned v = mnf;
    unsigned prefix32 = 0;
    int need = 32;
    int act = 1;
    for (int bit = 31; bit >= 0; --bit) {
      const unsigned bv = (v >> bit) & 1u;
      unsigned long long m0 = __ballot(act && (bv == 0u));
      int c0n = (int)__popcll(m0);
      if (c0n >= need) {
        act = act && (bv == 0u);
      } else {
        need -= c0n;
        act = act && (bv == 1u);
        prefix32 |= (1u << bit);
      }
    }
    tau32 = prefix32;
  }
  // pass B: recompute, ballot-rank append survivors to LDS
  int cnt = 0;
  for (int c0 = 0; c0 < NPTS; c0 += 64) {
    const int j = c0 + lane;
    const float4* xj = (const float4*)(xb + (size_t)j * 64);
    float dot = 0.f;
#pragma unroll
    for (int c4 = 0; c4 < 16; ++c4) {
      float4 c = xj[c4];
      dot = fmaf(q[c4].x, c.x, dot);
      dot = fmaf(q[c4].y, c.y, dot);
      dot = fmaf(q[c4].z, c.z, dot);
      dot = fmaf(q[c4].w, c.w, dot);
    }
    float d = fmaf(-2.f, dot, sqi + sqb[j]);
    unsigned u  = __float_as_uint(d);
    unsigned ck = (u & 0x80000000u) ? ~u : (u | 0x80000000u);
    bool keep = ck <= tau32;
    unsigned long long mask = __ballot(keep);
    if (mask != 0ULL) {
      int rank = (int)__popcll(mask & ((1ULL << lane) - 1ULL));
      if (keep) {
        int pos = cnt + rank;
        if (pos < 128)
          fsurv[wave][pos] = ((unsigned long long)ck << 12) | (unsigned)j;
      }
      cnt += (int)__popcll(mask);
    }
  }
  if (cnt <= 128) {
    unsigned long long vk0 = (lane      < cnt) ? fsurv[wave][lane]      : 0xFFFFFFFFFFFULL;
    unsigned long long vk1 = (lane + 64 < cnt) ? fsurv[wave][lane + 64] : 0xFFFFFFFFFFFULL;
    unsigned long long prefix = 0;
    int need = 32;
    for (int bit = 43; bit >= 0; --bit) {
      unsigned long long hm = (bit == 43) ? 0ULL
          : (~((1ULL << (bit + 1)) - 1ULL) & 0xFFFFFFFFFFFULL);
      bool a0 = (((vk0 ^ prefix) & hm) == 0ULL) && (((vk0 >> bit) & 1ULL) == 0ULL);
      bool a1 = (((vk1 ^ prefix) & hm) == 0ULL) && (((vk1 >> bit) & 1ULL) == 0ULL);
      int cnt0 = (int)__popcll(__ballot(a0)) + (int)__popcll(__ballot(a1));
      if (cnt0 < need) { need -= cnt0; prefix |= 1ULL << bit; }
    }
    bool sel0 = vk0 <= prefix;
    unsigned long long m0 = __ballot(sel0);
    int rank0 = (int)__popcll(m0 & ((1ULL << lane) - 1ULL));
    if (sel0)
      idx_out[(size_t)row * KNN + rank0] = (unsigned short)(vk0 & 0xFFFULL);
    int prev = (int)__popcll(m0);
    bool sel1 = vk1 <= prefix;
    unsigned long long m1 = __ballot(sel1);
    int rank1 = (int)__popcll(m1 & ((1ULL << lane) - 1ULL));
    if (sel1)
      idx_out[(size_t)row * KNN + prev + rank1] = (unsigned short)(vk1 & 0xFFFULL);
  } else {
    // tertiary: exact full scan, validated serial ballot-insert
    unsigned long long ent = (0xFFFFFFFFFFFULL << 5) | (unsigned long long)(lane & 31);
    unsigned long long M   = (0xFFFFFFFFFFFULL << 5) | 31ULL;
    for (int c0 = 0; c0 < NPTS; c0 += 64) {
      const int j = c0 + lane;
      const float4* xj = (const float4*)(xb + (size_t)j * 64);
      float dot = 0.f;
#pragma unroll
      for (int c4 = 0; c4 < 16; ++c4) {
        float4 c = xj[c4];
        dot = fmaf(q[c4].x, c.x, dot);
        dot = fmaf(q[c4].y, c.y, dot);
        dot = fmaf(q[c4].z, c.z, dot);
        dot = fmaf(q[c4].w, c.w, dot);
      }
      float d = fmaf(-2.f, dot, sqi + sqb[j]);
      unsigned u  = __float_as_uint(d);
      unsigned ck = (u & 0x80000000u) ? ~u : (u | 0x80000000u);
      unsigned long long cq = ((unsigned long long)ck << 12) | (unsigned)j;
      unsigned long long mask = __ballot(cq < (M >> 5));
      while (mask) {
        const int src = __builtin_ctzll(mask);
        mask &= mask - 1;
        const unsigned long long bq = shfl_u64(cq, src);
        if (bq < (M >> 5)) {
          const unsigned slot = (unsigned)(M & 31ULL);
          if ((unsigned)(lane & 31) == slot) ent = (bq << 5) | slot;
          unsigned long long v = ent;
#pragma unroll
          for (int off = 16; off >= 1; off >>= 1) {
            unsigned long long w2 = shfl_xor_u64(v, off);
            v = (v > w2) ? v : w2;
          }
          M = v;
        }
      }
    }
    if (lane < 32)
      idx_out[(size_t)row * KNN + lane] =
          (unsigned short)((ent >> 5) & 0xFFFULL);
  }
}

// =====================================================================
// F=3 kNN: pass 1 (per-lane min + need=32 radix tau); pass 2 ballot-rank
// append of packed 44-bit keys to LDS (cap 128/row); exact lex radix-
// select. Overflow -> per-row exact full-scan fallback.
// =====================================================================
template <int F>
__global__ __launch_bounds__(256, 4) void knn_tiled(const float* __restrict__ x,
                                                    const float* __restrict__ sq,
                                                    unsigned short* __restrict__ idx_out) {
  constexpr int FP = 4;
  constexpr int TC = 256;
  constexpr int RPB = 32;
  constexpr int RPW = 8;
  constexpr int SCAP = 128;

  __shared__ __attribute__((aligned(16))) float qv[RPB][FP];
  __shared__ float qsq[RPB];
  __shared__ __attribute__((aligned(16))) float ct[TC][FP];
  __shared__ float csq[TC];
  __shared__ unsigned long long surv[RPB][SCAP];   // 32 KB

  const int t    = threadIdx.x;
  const int wave = t >> 6;
  const int lane = t & 63;
  const int rowbase = blockIdx.x << 5;
  const int b     = rowbase >> 12;
  const int ibase = rowbase & (NPTS - 1);
  const float* xb  = x + (size_t)b * NPTS * F;
  const float* sqb = sq + (b << 12);

  if (t < RPB) {
    qv[t][0] = xb[(size_t)(ibase + t) * 3 + 0];
    qv[t][1] = xb[(size_t)(ibase + t) * 3 + 1];
    qv[t][2] = xb[(size_t)(ibase + t) * 3 + 2];
    qv[t][3] = 0.f;
    qsq[t] = sqb[ibase + t];
  }
  __syncthreads();

  const int r0 = wave << 3;
  float4 q[RPW];
  float sqi[RPW];
#pragma unroll
  for (int rr = 0; rr < RPW; ++rr) {
    q[rr] = *reinterpret_cast<const float4*>(&qv[r0 + rr][0]);
    sqi[rr] = qsq[r0 + rr];
  }

  unsigned mn[RPW];
#pragma unroll
  for (int rr = 0; rr < RPW; ++rr) mn[rr] = 0xFFFFFFFFu;

  // ---------------- pass 1: per-lane min of ck ----------------
  for (int tile = 0; tile < NPTS / TC; ++tile) {
    __syncthreads();
    {
      int jg = tile * TC + t;
      ct[t][0] = xb[(size_t)jg * 3 + 0];
      ct[t][1] = xb[(size_t)jg * 3 + 1];
      ct[t][2] = xb[(size_t)jg * 3 + 2];
      ct[t][3] = 0.f;
      csq[t] = sqb[jg];
    }
    __syncthreads();

    float4 c0 = *reinterpret_cast<const float4*>(&ct[lane][0]);
    float4 c1 = *reinterpret_cast<const float4*>(&ct[lane + 64][0]);
    float4 c2 = *reinterpret_cast<const float4*>(&ct[lane + 128][0]);
    float4 c3 = *reinterpret_cast<const float4*>(&ct[lane + 192][0]);
    float cs[4];
#pragma unroll
    for (int s = 0; s < 4; ++s) cs[s] = csq[lane + 64 * s];

#pragma unroll
    for (int rr = 0; rr < RPW; ++rr) {
      float4 qq = q[rr];
      float dd[4];
      dd[0] = fmaf(qq.z, c0.z, fmaf(qq.y, c0.y, qq.x * c0.x));
      dd[1] = fmaf(qq.z, c1.z, fmaf(qq.y, c1.y, qq.x * c1.x));
      dd[2] = fmaf(qq.z, c2.z, fmaf(qq.y, c2.y, qq.x * c2.x));
      dd[3] = fmaf(qq.z, c3.z, fmaf(qq.y, c3.y, qq.x * c3.x));
#pragma unroll
      for (int s = 0; s < 4; ++s) {
        float d = fmaf(-2.f, dd[s], sqi[rr] + cs[s]);
        unsigned u  = __float_as_uint(d);
        unsigned ck = (u & 0x80000000u) ? ~u : (u | 0x80000000u);
        mn[rr] = ck < mn[rr] ? ck : mn[rr];
      }
    }
  }

  // tau[rr] = exact 32nd-smallest of the 64 lane-mins (radix over bits).
  unsigned tau[RPW];
#pragma unroll
  for (int rr = 0; rr < RPW; ++rr) {
    const unsigned v = mn[rr];
    unsigned prefix = 0;
    int need = 32;
    int act = 1;
    for (int bit = 31; bit >= 0; --bit) {
      const unsigned bv = (v >> bit) & 1u;
      unsigned long long m0 = __ballot(act && (bv == 0u));
      int c0n = (int)__popcll(m0);
      if (c0n >= need) {
        act = act && (bv == 0u);
      } else {
        need -= c0n;
        act = act && (bv == 1u);
        prefix |= (1u << bit);
      }
    }
    tau[rr] = prefix;
  }

  // ---------------- pass 2: ballot-rank append survivors ----------------
  int cnt[RPW];
#pragma unroll
  for (int rr = 0; rr < RPW; ++rr) cnt[rr] = 0;

  for (int tile = 0; tile < NPTS / TC; ++tile) {
    __syncthreads();
    {
      int jg = tile * TC + t;
      ct[t][0] = xb[(size_t)jg * 3 + 0];
      ct[t][1] = xb[(size_t)jg * 3 + 1];
      ct[t][2] = xb[(size_t)jg * 3 + 2];
      ct[t][3] = 0.f;
      csq[t] = sqb[jg];
    }
    __syncthreads();

    float4 c0 = *reinterpret_cast<const float4*>(&ct[lane][0]);
    float4 c1 = *reinterpret_cast<const float4*>(&ct[lane + 64][0]);
    float4 c2 = *reinterpret_cast<const float4*>(&ct[lane + 128][0]);
    float4 c3 = *reinterpret_cast<const float4*>(&ct[lane + 192][0]);
    float cs[4];
#pragma unroll
    for (int s = 0; s < 4; ++s) cs[s] = csq[lane + 64 * s];

#pragma unroll
    for (int rr = 0; rr < RPW; ++rr) {
      float4 qq = q[rr];
      float dd[4];
      dd[0] = fmaf(qq.z, c0.z, fmaf(qq.y, c0.y, qq.x * c0.x));
      dd[1] = fmaf(qq.z, c1.z, fmaf(qq.y, c1.y, qq.x * c1.x));
      dd[2] = fmaf(qq.z, c2.z, fmaf(qq.y, c2.y, qq.x * c2.x));
      dd[3] = fmaf(qq.z, c3.z, fmaf(qq.y, c3.y, qq.x * c3.x));
#pragma unroll
      for (int s = 0; s < 4; ++s) {
        float d = fmaf(-2.f, dd[s], sqi[rr] + cs[s]);
        unsigned u  = __float_as_uint(d);
        unsigned ck = (u & 0x80000000u) ? ~u : (u | 0x80000000u);
        bool keep = ck <= tau[rr];
        unsigned long long mask = __ballot(keep);
        if (mask != 0ULL) {
          int rank = (int)__popcll(mask & ((1ULL << lane) - 1ULL));
          if (keep) {
            int pos = cnt[rr] + rank;
            if (pos < SCAP)
              surv[r0 + rr][pos] =
                  ((unsigned long long)ck << 12) |
                  (unsigned)(tile * TC + s * 64 + lane);
          }
          cnt[rr] += (int)__popcll(mask);
        }
      }
    }
  }

  // ---------------- exact lex top-32 per row via radix-select ----------------
#pragma unroll
  for (int rr = 0; rr < RPW; ++rr) {
    const int row = rowbase + r0 + rr;
    const int n = cnt[rr];
    if (n <= SCAP) {
      unsigned long long vk0 = (lane      < n) ? surv[r0 + rr][lane]      : 0xFFFFFFFFFFFULL;
      unsigned long long vk1 = (lane + 64 < n) ? surv[r0 + rr][lane + 64] : 0xFFFFFFFFFFFULL;
      unsigned long long prefix = 0;
      int need = 32;
      for (int bit = 43; bit >= 0; --bit) {
        unsigned long long hm = (bit == 43) ? 0ULL
            : (~((1ULL << (bit + 1)) - 1ULL) & 0xFFFFFFFFFFFULL);
        bool a0 = (((vk0 ^ prefix) & hm) == 0ULL) && (((vk0 >> bit) & 1ULL) == 0ULL);
        bool a1 = (((vk1 ^ prefix) & hm) == 0ULL) && (((vk1 >> bit) & 1ULL) == 0ULL);
        int cnt0 = (int)__popcll(__ballot(a0)) + (int)__popcll(__ballot(a1));
        if (cnt0 < need) { need -= cnt0; prefix |= 1ULL << bit; }
      }
      bool sel0 = vk0 <= prefix;
      unsigned long long m0 = __ballot(sel0);
      int rank0 = (int)__popcll(m0 & ((1ULL << lane) - 1ULL));
      if (sel0)
        idx_out[(row << 5) + rank0] = (unsigned short)(vk0 & 0xFFFULL);
      int prev = (int)__popcll(m0);
      bool sel1 = vk1 <= prefix;
      unsigned long long m1 = __ballot(sel1);
      int rank1 = (int)__popcll(m1 & ((1ULL << lane) - 1ULL));
      if (sel1)
        idx_out[(row << 5) + prev + rank1] = (unsigned short)(vk1 & 0xFFFULL);
    } else {
      // overflow fallback: exact full scan with validated ballot-insert
      unsigned long long ent = (0xFFFFFFFFFFFULL << 5) | (unsigned long long)(lane & 31);
      unsigned long long M   = (0xFFFFFFFFFFFULL << 5) | 31ULL;
      const float4 qq = q[rr];
      const float si = sqi[rr];
      for (int c0i = 0; c0i < NPTS; c0i += 64) {
        const int j = c0i + lane;
        const float dd_ = fmaf(qq.z, xb[(size_t)j * 3 + 2],
                           fmaf(qq.y, xb[(size_t)j * 3 + 1],
                                qq.x * xb[(size_t)j * 3 + 0]));
        float d = fmaf(-2.f, dd_, si + sqb[j]);
        unsigned u  = __float_as_uint(d);
        unsigned ck = (u & 0x80000000u) ? ~u : (u | 0x80000000u);
        unsigned long long cq = ((unsigned long long)ck << 12) | (unsigned)j;
        unsigned long long mask = __ballot(cq < (M >> 5));
        while (mask) {
          const int src = __builtin_ctzll(mask);
          mask &= mask - 1;
          const unsigned long long bq = shfl_u64(cq, src);
          if (bq < (M >> 5)) {
            const unsigned slot = (unsigned)(M & 31ULL);
            if ((unsigned)(lane & 31) == slot) ent = (bq << 5) | slot;
            unsigned long long v = ent;
#pragma unroll
            for (int off = 16; off >= 1; off >>= 1) {
              unsigned long long w2 = shfl_xor_u64(v, off);
              v = (v > w2) ? v : w2;
            }
            M = v;
          }
        }
      }
      if (lane < 32)
        idx_out[(row << 5) + lane] = (unsigned short)((ent >> 5) & 0xFFFULL);
    }
  }
}

// ---------------- per-node P = x.Wbot ; C = x.(Wtop-Wbot) + b ----------------
__global__ __launch_bounds__(256) void mlp_pc_kernel(const float* __restrict__ xin,
                                                     const float* __restrict__ W,
                                                     const float* __restrict__ bias,
                                                     float* __restrict__ P,
                                                     float* C,
                                                     int F, int O, int total) {
  int t = blockIdx.x * 256 + threadIdx.x;
  if (t >= total) return;
  int n = t / O, o = t % O;
  const float* xr = xin + (size_t)n * F;
  const float* Wt = W + o;
  const float* Wb = W + (size_t)F * O + o;
  float p = 0.f, c = 0.f;
  for (int f = 0; f < F; ++f) {
    float a  = xr[f];
    float wt = Wt[(size_t)f * O];
    float wb = Wb[(size_t)f * O];
    p = fmaf(a, wb, p);
    c = fmaf(a, wt - wb, c);
  }
  P[t] = p;
  C[t] = c + bias[o];
}

// ---------------- h[t] (pre-filled with C) += max_k P[idx_k] ----------------
__global__ __launch_bounds__(256) void aggregate_kernel(const unsigned short* __restrict__ idx,
                                                        const float* __restrict__ P,
                                                        float* h, int O, int total) {
  int t = blockIdx.x * 256 + threadIdx.x;
  if (t >= total) return;
  int n = t / O, o = t % O;
  const unsigned short* ix = idx + (size_t)n * KNN;
  const int rowbase = (n >> 12) << 12;
  float m = -3.402823466e+38f;
  for (int k = 0; k < KNN; ++k) {
    int jg = rowbase + ix[k];
    float v = P[(size_t)jg * O + o];
    m = fmaxf(m, v);
  }
  h[t] = h[t] + m;
}

// ---------------- BN stats over relu(h): mean + invstd per channel ----------
__global__ __launch_bounds__(256) void bn_stats_kernel(const float* __restrict__ h,
                                                       float* __restrict__ stats) {
  const int c = blockIdx.x;
  const int t = threadIdx.x;
  double s = 0.0, s2 = 0.0;
  for (int n = t; n < NROWS; n += 256) {
    float v = h[(size_t)n * 64 + c];
    v = v > 0.f ? v : 0.f;
    s += v;
    s2 += (double)v * v;
  }
  __shared__ double ls[256], ls2[256];
  ls[t] = s; ls2[t] = s2;
  __syncthreads();
  for (int st = 128; st; st >>= 1) {
    if (t < st) { ls[t] += ls[t + st]; ls2[t] += ls2[t + st]; }
    __syncthreads();
  }
  if (t == 0) {
    double mean = ls[0] / (double)NROWS;
    double var  = ls2[0] / (double)NROWS - mean * mean;
    stats[c]      = (float)mean;
    stats[64 + c] = (float)(1.0 / sqrt(var + 1e-5));
  }
}

// ---------------- apply: out = (relu(h)-mean)*invstd*g + be ----------------
__global__ __launch_bounds__(256) void bn_apply_kernel(const float* h,
                                                       const float* __restrict__ stats,
                                                       const float* __restrict__ g,
                                                       const float* __restrict__ be,
                                                       float* out, int total) {
  int t = blockIdx.x * 256 + threadIdx.x;
  if (t >= total) return;
  int ch = t & 63;
  float v = fmaxf(h[t], 0.f);
  out[t] = (v - stats[ch]) * stats[64 + ch] * g[ch] + be[ch];
}

// ---------------- write h3 to out + per-block loss partials ----------------
__global__ __launch_bounds__(256) void final_kernel(const float* __restrict__ h3,
                                                    const float* __restrict__ target,
                                                    float* __restrict__ out,
                                                    double* __restrict__ partial) {
  double s = 0.0;
  for (int t = blockIdx.x * 256 + threadIdx.x; t < NROWS * 3; t += 256 * 256) {
    float v = h3[t];
    out[t] = v;
    float d = v - target[t];
    s += (double)d * d;
  }
  __shared__ double ls[256];
  int t = threadIdx.x;
  ls[t] = s;
  __syncthreads();
  for (int st = 128; st; st >>= 1) {
    if (t < st) ls[t] += ls[t + st];
    __syncthreads();
  }
  if (t == 0) partial[blockIdx.x] = ls[0];
}

__global__ __launch_bounds__(256) void loss_kernel(const double* __restrict__ partial,
                                                   float* __restrict__ out) {
  int t = threadIdx.x;
  __shared__ double ls[256];
  ls[t] = partial[t];
  __syncthreads();
  for (int st = 128; st; st >>= 1) {
    if (t < st) ls[t] += ls[t + st];
    __syncthreads();
  }
  if (t == 0) out[NROWS * 3] = (float)(ls[0] / (double)(NROWS * 3));
}

// ---------------- driver ----------------
extern "C" void kernel_launch(void* const* d_in, const int* in_sizes, int n_in,
                              void* d_out, int out_size, void* d_ws, size_t ws_size,
                              hipStream_t stream) {
  const float* x   = (const float*)d_in[0];
  const float* tgt = (const float*)d_in[1];
  const float* W1  = (const float*)d_in[2];
  const float* b1  = (const float*)d_in[3];
  const float* g1  = (const float*)d_in[4];
  const float* be1 = (const float*)d_in[5];
  const float* W2  = (const float*)d_in[6];
  const float* b2  = (const float*)d_in[7];
  const float* g2  = (const float*)d_in[8];
  const float* be2 = (const float*)d_in[9];
  const float* W3  = (const float*)d_in[10];
  const float* b3  = (const float*)d_in[11];
  float* out = (float*)d_out;

  char* ws = (char*)d_ws;
  size_t off = 0;
  float* sq    = (float*)(ws + off); off += (size_t)NROWS * 4;           // 128 KB
  unsigned short* idxb = (unsigned short*)(ws + off); off += (size_t)NROWS * KNN * 2; // 2 MB
  float* P     = (float*)(ws + off); off += (size_t)NROWS * 64 * 4;      // 8 MB
  float* CA    = (float*)(ws + off); off += (size_t)NROWS * 64 * 4;      // 8 MB
  float* CB    = (float*)(ws + off); off += (size_t)NROWS * 64 * 4;      // 8 MB
  int*   gcnt  = (int*)(ws + off);   off += (size_t)NROWS * 8;           // 256 KB (2 halves)
  unsigned short* glist = (unsigned short*)(ws + off); off += (size_t)NROWS * CAP * 2; // 16.8 MB
  float* stats = (float*)(ws + off); off += 256 * 4;
  float* sqmax = (float*)(ws + off); off += 64;
  double* part = (double*)(ws + off); off += 256 * 8;

  // hi/lo (bf16 frag-major, 4 MB each) alias P (8 MB): P is dead during screen/rerank.
  unsigned short* hib = (unsigned short*)P;
  unsigned short* lob = hib + (size_t)NROWS * 64;

  const int T64 = NROWS * 64;
  const int T3  = NROWS * 3;

  // ---- layer 1 (F=3 -> 64), VALU kNN ----
  sqnorm_kernel<<<NROWS / 256, 256, 0, stream>>>(x, sq, 3);
  knn_tiled<3><<<NROWS / 32, 256, 0, stream>>>(x, sq, idxb);
  mlp_pc_kernel<<<T64 / 256, 256, 0, stream>>>(x, W1, b1, P, CA, 3, 64, T64);
  aggregate_kernel<<<T64 / 256, 256, 0, stream>>>(idxb, P, CA, 64, T64);
  bn_stats_kernel<<<64, 256, 0, stream>>>(CA, stats);
  bn_apply_kernel<<<T64 / 256, 256, 0, stream>>>(CA, stats, g1, be1, CA, T64);

  // ---- layer 2 (F=64 -> 64), MFMA screen + exact rerank ----
  sqnorm_kernel<<<NROWS / 256, 256, 0, stream>>>(CA, sq, 64);
  split_kernel<<<T64 / 256, 256, 0, stream>>>(CA, hib, lob, T64);
  batchmax_kernel<<<NB, 256, 0, stream>>>(sq, sqmax);
  knn_screen<<<1024, 256, 0, stream>>>(hib, lob, sq, sqmax, gcnt, glist);
  knn_rerank<<<NROWS / 4, 256, 0, stream>>>(CA, sq, gcnt, glist, idxb);
  knn_rerank_fb<<<NROWS / 4, 256, 0, stream>>>(CA, sq, gcnt, idxb);
  mlp_pc_kernel<<<T64 / 256, 256, 0, stream>>>(CA, W2, b2, P, CB, 64, 64, T64);
  aggregate_kernel<<<T64 / 256, 256, 0, stream>>>(idxb, P, CB, 64, T64);
  bn_stats_kernel<<<64, 256, 0, stream>>>(CB, stats);
  bn_apply_kernel<<<T64 / 256, 256, 0, stream>>>(CB, stats, g2, be2, CB, T64);

  // ---- layer 3 (F=64 -> 3), MFMA screen + exact rerank ----
  sqnorm_kernel<<<NROWS / 256, 256, 0, stream>>>(CB, sq, 64);
  split_kernel<<<T64 / 256, 256, 0, stream>>>(CB, hib, lob, T64);
  batchmax_kernel<<<NB, 256, 0, stream>>>(sq, sqmax);
  knn_screen<<<1024, 256, 0, stream>>>(hib, lob, sq, sqmax, gcnt, glist);
  knn_rerank<<<NROWS / 4, 256, 0, stream>>>(CB, sq, gcnt, glist, idxb);
  knn_rerank_fb<<<NROWS / 4, 256, 0, stream>>>(CB, sq, gcnt, idxb);
  mlp_pc_kernel<<<T3 / 256, 256, 0, stream>>>(CB, W3, b3, P, CA, 64, 3, T3);
  aggregate_kernel<<<T3 / 256, 256, 0, stream>>>(idxb, P, CA, 3, T3);

  // ---- output + loss ----
  final_kernel<<<256, 256, 0, stream>>>(CA, tgt, out, part);
  loss_kernel<<<1, 256, 0, stream>>>(part, out);
}